// Round 1
// baseline (281.351 us; speedup 1.0000x reference)
//
#include <hip/hip_runtime.h>
#include <hip/hip_bf16.h>
#include <stdint.h>

typedef __bf16 bf16_t;
typedef __bf16 bf16x8 __attribute__((ext_vector_type(8)));
typedef __bf16 bf16x4 __attribute__((ext_vector_type(4)));
typedef float f32x4 __attribute__((ext_vector_type(4)));

#define GLD_LDS16(src, dst)                                                              \
  __builtin_amdgcn_global_load_lds((const __attribute__((address_space(1))) void*)(src), \
                                   (__attribute__((address_space(3))) void*)(dst), 16, 0, 0)

// ---------------------------------------------------------------------------
// fp32 -> bf16 convert (vectorized float4 -> bf16x4)
// ---------------------------------------------------------------------------
__global__ __launch_bounds__(256) void cvt_f32_bf16(const float* __restrict__ in,
                                                    bf16_t* __restrict__ out, long n4) {
  long i = (long)blockIdx.x * blockDim.x + threadIdx.x;
  const long stride = (long)gridDim.x * blockDim.x;
  for (; i < n4; i += stride) {
    float4 v = ((const float4*)in)[i];
    bf16x4 o;
    o[0] = (bf16_t)v.x; o[1] = (bf16_t)v.y; o[2] = (bf16_t)v.z; o[3] = (bf16_t)v.w;
    ((bf16x4*)out)[i] = o;
  }
}

// ---------------------------------------------------------------------------
// bf16 transpose [rows,cols] -> [cols,rows], 32x32 LDS tiles, batched (z)
// ---------------------------------------------------------------------------
__global__ __launch_bounds__(256) void transpose_bf16(const bf16_t* __restrict__ in,
                                                      bf16_t* __restrict__ out,
                                                      int rows, int cols, long sIn, long sOut) {
  __shared__ bf16_t tile[32][33];
  const int z = blockIdx.z;
  in  += (long)z * sIn;
  out += (long)z * sOut;
  const int c0 = blockIdx.x << 5, r0 = blockIdx.y << 5;
  const int tc = threadIdx.x & 31, tr = threadIdx.x >> 5;  // 8 rows x 32 cols per pass
#pragma unroll
  for (int it = 0; it < 4; ++it)
    tile[tr + it * 8][tc] = in[(long)(r0 + tr + it * 8) * cols + c0 + tc];
  __syncthreads();
#pragma unroll
  for (int it = 0; it < 4; ++it)
    out[(long)(c0 + tr + it * 8) * rows + r0 + tc] = tile[tc][tr + it * 8];
}

// ---------------------------------------------------------------------------
// Causal row softmax, in-place on bf16 scores. One 256-thread block per row.
// Row length n=2048 (8 elems/thread). Valid entries j<=i; j>i written as 0.
// ---------------------------------------------------------------------------
__global__ __launch_bounds__(256) void softmax_causal(bf16_t* __restrict__ S, int n, long sB) {
  const int i = blockIdx.x;
  const int z = blockIdx.y;
  bf16_t* row = S + (long)z * sB + (long)i * n;
  const int t = threadIdx.x;
  float vals[8];
  float mx = -3.0e38f;
#pragma unroll
  for (int it = 0; it < 8; ++it) {
    int j = (it << 8) + t;
    float v = (j <= i) ? (float)row[j] : -3.0e38f;
    vals[it] = v;
    mx = fmaxf(mx, v);
  }
#pragma unroll
  for (int off = 32; off; off >>= 1) mx = fmaxf(mx, __shfl_xor(mx, off));
  __shared__ float redm[4];
  if ((t & 63) == 0) redm[t >> 6] = mx;
  __syncthreads();
  mx = fmaxf(fmaxf(redm[0], redm[1]), fmaxf(redm[2], redm[3]));

  float sum = 0.f;
#pragma unroll
  for (int it = 0; it < 8; ++it) {
    int j = (it << 8) + t;
    float p = (j <= i) ? __expf(vals[it] - mx) : 0.f;
    vals[it] = p;
    sum += p;
  }
#pragma unroll
  for (int off = 32; off; off >>= 1) sum += __shfl_xor(sum, off);
  __shared__ float reds[4];
  if ((t & 63) == 0) reds[t >> 6] = sum;
  __syncthreads();
  sum = reds[0] + reds[1] + reds[2] + reds[3];
  const float inv = 1.0f / sum;
#pragma unroll
  for (int it = 0; it < 8; ++it) {
    int j = (it << 8) + t;
    row[j] = (bf16_t)(vals[it] * inv);
  }
}

// ---------------------------------------------------------------------------
// GEMM: C[M,N] = alpha * A[M,K] * B[N,K]^T (+ bias[N]).
// m97 structure: 128x128 tile, BK=32, 256 threads = 4 waves (2x2 of 64x64),
// global_load_lds width 16, mfma_f32_16x16x32_bf16, fp32 accum.
// CAUSAL_SKIP: skip tiles entirely above the diagonal (scores GEMM).
// KBOUND: K-loop bounded by n0+128 (PV GEMM exploiting P[i][j]=0 for j>i).
// ---------------------------------------------------------------------------
template <bool BF16_OUT, bool BIAS, bool CAUSAL_SKIP, bool KBOUND>
__global__ __launch_bounds__(256, 2) void gemm_bt(const bf16_t* __restrict__ A,
                                                  const bf16_t* __restrict__ B,
                                                  const float* __restrict__ bias,
                                                  void* __restrict__ Cout,
                                                  int M, int N, int K, float alpha,
                                                  long sAb, long sBb, long sCb) {
  const int bx = blockIdx.x;  // N-tile
  const int by = blockIdx.y;  // M-tile
  const int m0 = by << 7, n0 = bx << 7;
  if (CAUSAL_SKIP && n0 > m0 + 127) return;

  const int bz = blockIdx.z;
  A += (long)bz * sAb;
  B += (long)bz * sBb;

  int KT = K >> 5;
  if (KBOUND) {
    int kb = (n0 + 128) >> 5;
    if (kb < KT) KT = kb;
  }

  __shared__ __align__(16) bf16_t As[128 * 32];
  __shared__ __align__(16) bf16_t Bs[128 * 32];

  const int t = threadIdx.x;
  const int l = t & 63;
  const int w = t >> 6;
  const int wr = w >> 1, wc = w & 1;

  // --- staging plan: 512 chunks of 16B per tile; chunk c -> row c/4, k (c%4)*8
  const int c0 = t, c1 = t + 256;
  const bf16_t* a_src0 = A + (long)(m0 + (c0 >> 2)) * K + ((c0 & 3) << 3);
  const bf16_t* a_src1 = A + (long)(m0 + (c1 >> 2)) * K + ((c1 & 3) << 3);
  const bf16_t* b_src0 = B + (long)(n0 + (c0 >> 2)) * K + ((c0 & 3) << 3);
  const bf16_t* b_src1 = B + (long)(n0 + (c1 >> 2)) * K + ((c1 & 3) << 3);
  char* const asb = (char*)As;
  char* const bsb = (char*)Bs;
  char* const a_dst0 = asb + w * 1024;         // wave-uniform base (+ lane*16 implicit)
  char* const a_dst1 = asb + 4096 + w * 1024;
  char* const b_dst0 = bsb + w * 1024;
  char* const b_dst1 = bsb + 4096 + w * 1024;

  // --- fragment read offsets (A/B: row=lane&15, k = 8*(lane>>4) + 0..7)
  const int r16 = l & 15, kg = l >> 4;
  int aoff[4], boff[4];
#pragma unroll
  for (int mi = 0; mi < 4; ++mi) aoff[mi] = (((wr * 64 + mi * 16 + r16) * 32) + kg * 8) * 2;
#pragma unroll
  for (int ni = 0; ni < 4; ++ni) boff[ni] = (((wc * 64 + ni * 16 + r16) * 32) + kg * 8) * 2;

  f32x4 acc[4][4] = {};

  for (int kt = 0; kt < KT; ++kt) {
    __syncthreads();  // previous tile fully consumed
    GLD_LDS16(a_src0, a_dst0);
    GLD_LDS16(a_src1, a_dst1);
    GLD_LDS16(b_src0, b_dst0);
    GLD_LDS16(b_src1, b_dst1);
    a_src0 += 32; a_src1 += 32; b_src0 += 32; b_src1 += 32;
    __syncthreads();  // tile staged (compiler drains vmcnt before barrier)

    bf16x8 af[4], bfr[4];
#pragma unroll
    for (int mi = 0; mi < 4; ++mi) af[mi] = *(const bf16x8*)(asb + aoff[mi]);
#pragma unroll
    for (int ni = 0; ni < 4; ++ni) bfr[ni] = *(const bf16x8*)(bsb + boff[ni]);
#pragma unroll
    for (int mi = 0; mi < 4; ++mi)
#pragma unroll
      for (int ni = 0; ni < 4; ++ni)
        acc[mi][ni] = __builtin_amdgcn_mfma_f32_16x16x32_bf16(af[mi], bfr[ni], acc[mi][ni], 0, 0, 0);
  }

  // --- epilogue: C/D layout col=lane&15, row=(lane>>4)*4 + reg
  const int rowbase = m0 + wr * 64 + ((l >> 4) << 2);
  const int colbase = n0 + wc * 64 + (l & 15);
  if constexpr (BF16_OUT) {
    bf16_t* C = (bf16_t*)Cout + (long)bz * sCb;
#pragma unroll
    for (int mi = 0; mi < 4; ++mi)
#pragma unroll
      for (int ni = 0; ni < 4; ++ni) {
        const int col = colbase + ni * 16;
        float badd = 0.f;
        if constexpr (BIAS) badd = bias[col];
#pragma unroll
        for (int j = 0; j < 4; ++j) {
          float v = acc[mi][ni][j] * alpha + badd;
          C[(long)(rowbase + mi * 16 + j) * N + col] = (bf16_t)v;
        }
      }
  } else {
    float* C = (float*)Cout + (long)bz * sCb;
#pragma unroll
    for (int mi = 0; mi < 4; ++mi)
#pragma unroll
      for (int ni = 0; ni < 4; ++ni) {
        const int col = colbase + ni * 16;
        float badd = 0.f;
        if constexpr (BIAS) badd = bias[col];
#pragma unroll
        for (int j = 0; j < 4; ++j) {
          float v = acc[mi][ni][j] * alpha + badd;
          C[(long)(rowbase + mi * 16 + j) * N + col] = v;
        }
      }
  }
}

// ---------------------------------------------------------------------------
extern "C" void kernel_launch(void* const* d_in, const int* in_sizes, int n_in,
                              void* d_out, int out_size, void* d_ws, size_t ws_size,
                              hipStream_t stream) {
  const int b = 4, n = 2048, d = 1024;
  const long nd  = (long)n * d;   // 2,097,152 (per-batch [n,d])
  const long bn  = (long)b * n;   // 8192
  const long bnd = bn * d;        // 8,388,608
  const long ddl = (long)d * d;   // 1,048,576
  const long nn  = (long)n * n;   // 4,194,304

  const float* q  = (const float*)d_in[0];
  const float* k  = (const float*)d_in[1];
  const float* v  = (const float*)d_in[2];
  const float* Wq = (const float*)d_in[3];
  const float* bq = (const float*)d_in[4];
  const float* Wk = (const float*)d_in[5];
  const float* bk = (const float*)d_in[6];
  const float* Wv = (const float*)d_in[7];
  const float* bv = (const float*)d_in[8];
  const float* Wo = (const float*)d_in[9];
  const float* bo = (const float*)d_in[10];

  // workspace layout (bf16 elements)
  bf16_t* ws  = (bf16_t*)d_ws;
  bf16_t* qB  = ws;              // bnd
  bf16_t* kB  = qB + bnd;        // bnd
  bf16_t* vB  = kB + bnd;        // bnd
  bf16_t* WqB = vB + bnd;        // dd
  bf16_t* WkB = WqB + ddl;
  bf16_t* WvB = WkB + ddl;
  bf16_t* WoB = WvB + ddl;
  bf16_t* qpB = WoB + ddl;       // bnd
  bf16_t* kpB = qpB + bnd;       // bnd
  bf16_t* vpB = kpB + bnd;       // bnd
  bf16_t* vpT = vpB + bnd;       // bnd   (per-batch [d,n])
  bf16_t* S   = vpT + bnd;       // b*nn  (scores -> probs, in place)
  bf16_t* yT  = S + (long)b * nn;// bnd   (per-batch [d,n]; flat == y2 [8192,1024])
  const size_t need = (size_t)(8 * bnd + 4 * ddl + (long)b * nn) * 2;
  if (ws_size < need) return;  // visible failure rather than corruption

  dim3 blk(256);

  // fp32 -> bf16 converts
  cvt_f32_bf16<<<2048, blk, 0, stream>>>(q, qB, bnd / 4);
  cvt_f32_bf16<<<2048, blk, 0, stream>>>(k, kB, bnd / 4);
  cvt_f32_bf16<<<2048, blk, 0, stream>>>(v, vB, bnd / 4);
  cvt_f32_bf16<<<1024, blk, 0, stream>>>(Wq, WqB, ddl / 4);
  cvt_f32_bf16<<<1024, blk, 0, stream>>>(Wk, WkB, ddl / 4);
  cvt_f32_bf16<<<1024, blk, 0, stream>>>(Wv, WvB, ddl / 4);
  cvt_f32_bf16<<<1024, blk, 0, stream>>>(Wo, WoB, ddl / 4);

  // projections: [8192,1024] = [8192,1024] x [1024,1024]^T + bias
  dim3 gProj(d / 128, bn / 128, 1);  // (8, 64)
  gemm_bt<true, true, false, false><<<gProj, blk, 0, stream>>>(qB, WqB, bq, qpB, bn, d, d, 1.f, 0, 0, 0);
  gemm_bt<true, true, false, false><<<gProj, blk, 0, stream>>>(kB, WkB, bk, kpB, bn, d, d, 1.f, 0, 0, 0);
  gemm_bt<true, true, false, false><<<gProj, blk, 0, stream>>>(vB, WvB, bv, vpB, bn, d, d, 1.f, 0, 0, 0);

  // vpT[z] = vpB[z]^T  ([n,d] -> [d,n])
  transpose_bf16<<<dim3(d / 32, n / 32, b), blk, 0, stream>>>(vpB, vpT, n, d, nd, nd);

  // scores: S[z] = qp[z] x kp[z]^T * (1/32), causal tile-skip
  gemm_bt<true, false, true, false><<<dim3(n / 128, n / 128, b), blk, 0, stream>>>(
      qpB, kpB, nullptr, S, n, n, d, 0.03125f, nd, nd, nn);

  // causal softmax in place (S -> P)
  softmax_causal<<<dim3(n, b), blk, 0, stream>>>(S, n, nn);

  // yT[z] = vpT[z] x P[z]^T   (K bounded per N-tile by causality)
  gemm_bt<true, false, false, true><<<dim3(n / 128, d / 128, b), blk, 0, stream>>>(
      vpT, S, nullptr, yT, d, n, n, 1.f, nd, nn, nd);

  // out = y2 x Wo^T + bo ; y2 flat == yT flat ([8192,1024]), fp32 out
  gemm_bt<false, true, false, false><<<gProj, blk, 0, stream>>>(yT, WoB, bo, (float*)d_out, bn, d, d, 1.f, 0, 0, 0);
}

// Round 2
// 255.408 us; speedup vs baseline: 1.1016x; 1.1016x over previous
//
#include <hip/hip_runtime.h>
#include <hip/hip_bf16.h>
#include <stdint.h>

typedef __bf16 bf16_t;
typedef __bf16 bf16x8 __attribute__((ext_vector_type(8)));
typedef __bf16 bf16x4 __attribute__((ext_vector_type(4)));
typedef float f32x4 __attribute__((ext_vector_type(4)));

#define GLD_LDS16(src, dst)                                                              \
  __builtin_amdgcn_global_load_lds((const __attribute__((address_space(1))) void*)(src), \
                                   (__attribute__((address_space(3))) void*)(dst), 16, 0, 0)

// ---------------------------------------------------------------------------
// fp32 -> bf16 convert, ALL tensors in one launch. blockIdx.y = segment.
// ---------------------------------------------------------------------------
struct CvtArgs {
  const float* src[7];
  bf16_t* dst[7];
  long n4[7];
};

__global__ __launch_bounds__(256) void cvt_all(CvtArgs a) {
  const int seg = blockIdx.y;
  const float* __restrict__ in = a.src[seg];
  bf16_t* __restrict__ out = a.dst[seg];
  const long n4 = a.n4[seg];
  long i = (long)blockIdx.x * blockDim.x + threadIdx.x;
  const long stride = (long)gridDim.x * blockDim.x;
  for (; i < n4; i += stride) {
    float4 v = ((const float4*)in)[i];
    bf16x4 o;
    o[0] = (bf16_t)v.x; o[1] = (bf16_t)v.y; o[2] = (bf16_t)v.z; o[3] = (bf16_t)v.w;
    ((bf16x4*)out)[i] = o;
  }
}

// ---------------------------------------------------------------------------
// bf16 transpose [rows,cols] -> [cols,rows], 32x32 LDS tiles, batched (z)
// ---------------------------------------------------------------------------
__global__ __launch_bounds__(256) void transpose_bf16(const bf16_t* __restrict__ in,
                                                      bf16_t* __restrict__ out,
                                                      int rows, int cols, long sIn, long sOut) {
  __shared__ bf16_t tile[32][33];
  const int z = blockIdx.z;
  in  += (long)z * sIn;
  out += (long)z * sOut;
  const int c0 = blockIdx.x << 5, r0 = blockIdx.y << 5;
  const int tc = threadIdx.x & 31, tr = threadIdx.x >> 5;
#pragma unroll
  for (int it = 0; it < 4; ++it)
    tile[tr + it * 8][tc] = in[(long)(r0 + tr + it * 8) * cols + c0 + tc];
  __syncthreads();
#pragma unroll
  for (int it = 0; it < 4; ++it)
    out[(long)(c0 + tr + it * 8) * rows + r0 + tc] = tile[tc][tr + it * 8];
}

// ---------------------------------------------------------------------------
// Causal row softmax, in-place on bf16 scores. One 256-thread block per row.
// ---------------------------------------------------------------------------
__global__ __launch_bounds__(256) void softmax_causal(bf16_t* __restrict__ S, int n, long sB) {
  const int i = blockIdx.x;
  const int z = blockIdx.y;
  bf16_t* row = S + (long)z * sB + (long)i * n;
  const int t = threadIdx.x;
  float vals[8];
  float mx = -3.0e38f;
#pragma unroll
  for (int it = 0; it < 8; ++it) {
    int j = (it << 8) + t;
    float v = (j <= i) ? (float)row[j] : -3.0e38f;
    vals[it] = v;
    mx = fmaxf(mx, v);
  }
#pragma unroll
  for (int off = 32; off; off >>= 1) mx = fmaxf(mx, __shfl_xor(mx, off));
  __shared__ float redm[4];
  if ((t & 63) == 0) redm[t >> 6] = mx;
  __syncthreads();
  mx = fmaxf(fmaxf(redm[0], redm[1]), fmaxf(redm[2], redm[3]));

  float sum = 0.f;
#pragma unroll
  for (int it = 0; it < 8; ++it) {
    int j = (it << 8) + t;
    float p = (j <= i) ? __expf(vals[it] - mx) : 0.f;
    vals[it] = p;
    sum += p;
  }
#pragma unroll
  for (int off = 32; off; off >>= 1) sum += __shfl_xor(sum, off);
  __shared__ float reds[4];
  if ((t & 63) == 0) reds[t >> 6] = sum;
  __syncthreads();
  sum = reds[0] + reds[1] + reds[2] + reds[3];
  const float inv = 1.0f / sum;
#pragma unroll
  for (int it = 0; it < 8; ++it) {
    int j = (it << 8) + t;
    row[j] = (bf16_t)(vals[it] * inv);
  }
}

// ---------------------------------------------------------------------------
// GEMM body: C[M,N] = alpha * A[M,K] * B[N,K]^T (+ bias[N]).
// m97 structure: 128x128 tile, BK=32, 256 threads = 4 waves (2x2 of 64x64),
// global_load_lds width 16, mfma_f32_16x16x32_bf16, fp32 accum.
// ---------------------------------------------------------------------------
template <bool BF16_OUT, bool BIAS, bool KBOUND>
__device__ __forceinline__ void gemm_body(const bf16_t* __restrict__ A,
                                          const bf16_t* __restrict__ B,
                                          const float* __restrict__ bias,
                                          void* __restrict__ Cout,
                                          int N, int K, float alpha,
                                          int m0, int n0) {
  int KT = K >> 5;
  if (KBOUND) {
    int kb = (n0 + 128) >> 5;
    if (kb < KT) KT = kb;
  }

  __shared__ __align__(16) bf16_t As[128 * 32];
  __shared__ __align__(16) bf16_t Bs[128 * 32];

  const int t = threadIdx.x;
  const int l = t & 63;
  const int w = t >> 6;
  const int wr = w >> 1, wc = w & 1;

  const int c0 = t, c1 = t + 256;
  const bf16_t* a_src0 = A + (long)(m0 + (c0 >> 2)) * K + ((c0 & 3) << 3);
  const bf16_t* a_src1 = A + (long)(m0 + (c1 >> 2)) * K + ((c1 & 3) << 3);
  const bf16_t* b_src0 = B + (long)(n0 + (c0 >> 2)) * K + ((c0 & 3) << 3);
  const bf16_t* b_src1 = B + (long)(n0 + (c1 >> 2)) * K + ((c1 & 3) << 3);
  char* const asb = (char*)As;
  char* const bsb = (char*)Bs;
  char* const a_dst0 = asb + w * 1024;
  char* const a_dst1 = asb + 4096 + w * 1024;
  char* const b_dst0 = bsb + w * 1024;
  char* const b_dst1 = bsb + 4096 + w * 1024;

  const int r16 = l & 15, kg = l >> 4;
  int aoff[4], boff[4];
#pragma unroll
  for (int mi = 0; mi < 4; ++mi) aoff[mi] = (((wr * 64 + mi * 16 + r16) * 32) + kg * 8) * 2;
#pragma unroll
  for (int ni = 0; ni < 4; ++ni) boff[ni] = (((wc * 64 + ni * 16 + r16) * 32) + kg * 8) * 2;

  f32x4 acc[4][4] = {};

  for (int kt = 0; kt < KT; ++kt) {
    __syncthreads();
    GLD_LDS16(a_src0, a_dst0);
    GLD_LDS16(a_src1, a_dst1);
    GLD_LDS16(b_src0, b_dst0);
    GLD_LDS16(b_src1, b_dst1);
    a_src0 += 32; a_src1 += 32; b_src0 += 32; b_src1 += 32;
    __syncthreads();

    bf16x8 af[4], bfr[4];
#pragma unroll
    for (int mi = 0; mi < 4; ++mi) af[mi] = *(const bf16x8*)(asb + aoff[mi]);
#pragma unroll
    for (int ni = 0; ni < 4; ++ni) bfr[ni] = *(const bf16x8*)(bsb + boff[ni]);
#pragma unroll
    for (int mi = 0; mi < 4; ++mi)
#pragma unroll
      for (int ni = 0; ni < 4; ++ni)
        acc[mi][ni] = __builtin_amdgcn_mfma_f32_16x16x32_bf16(af[mi], bfr[ni], acc[mi][ni], 0, 0, 0);
  }

  const int rowbase = m0 + wr * 64 + ((l >> 4) << 2);
  const int colbase = n0 + wc * 64 + (l & 15);
  if constexpr (BF16_OUT) {
    bf16_t* C = (bf16_t*)Cout;
#pragma unroll
    for (int mi = 0; mi < 4; ++mi)
#pragma unroll
      for (int ni = 0; ni < 4; ++ni) {
        const int col = colbase + ni * 16;
        float badd = 0.f;
        if constexpr (BIAS) badd = bias[col];
#pragma unroll
        for (int j = 0; j < 4; ++j) {
          float v = acc[mi][ni][j] * alpha + badd;
          C[(long)(rowbase + mi * 16 + j) * N + col] = (bf16_t)v;
        }
      }
  } else {
    float* C = (float*)Cout;
#pragma unroll
    for (int mi = 0; mi < 4; ++mi)
#pragma unroll
      for (int ni = 0; ni < 4; ++ni) {
        const int col = colbase + ni * 16;
        float badd = 0.f;
        if constexpr (BIAS) badd = bias[col];
#pragma unroll
        for (int j = 0; j < 4; ++j) {
          float v = acc[mi][ni][j] * alpha + badd;
          C[(long)(rowbase + mi * 16 + j) * N + col] = v;
        }
      }
  }
}

// z = batch index with element strides (scores / PV / out-proj)
template <bool BF16_OUT, bool BIAS, bool CAUSAL_SKIP, bool KBOUND>
__global__ __launch_bounds__(256, 2) void gemm_bt(const bf16_t* __restrict__ A,
                                                  const bf16_t* __restrict__ B,
                                                  const float* __restrict__ bias,
                                                  void* __restrict__ Cout,
                                                  int N, int K, float alpha,
                                                  long sAb, long sBb, long sCb, int eltC) {
  const int m0 = blockIdx.y << 7, n0 = blockIdx.x << 7;
  if (CAUSAL_SKIP && n0 > m0 + 127) return;
  const int bz = blockIdx.z;
  gemm_body<BF16_OUT, BIAS, KBOUND>(A + (long)bz * sAb, B + (long)bz * sBb, bias,
                                    (char*)Cout + (long)bz * sCb * eltC, N, K, alpha, m0, n0);
}

// z = operation index selecting from pointer arrays (fused QKV projections)
struct QkvArgs {
  const bf16_t* A[3];
  const bf16_t* B[3];
  const float* bias[3];
  bf16_t* C[3];
};

__global__ __launch_bounds__(256, 2) void gemm_qkv(QkvArgs a, int N, int K) {
  const int z = blockIdx.z;
  gemm_body<true, true, false>(a.A[z], a.B[z], a.bias[z], a.C[z], N, K, 1.0f,
                               blockIdx.y << 7, blockIdx.x << 7);
}

// ---------------------------------------------------------------------------
extern "C" void kernel_launch(void* const* d_in, const int* in_sizes, int n_in,
                              void* d_out, int out_size, void* d_ws, size_t ws_size,
                              hipStream_t stream) {
  const int b = 4, n = 2048, d = 1024;
  const long nd  = (long)n * d;
  const long bn  = (long)b * n;
  const long bnd = bn * d;
  const long ddl = (long)d * d;
  const long nn  = (long)n * n;

  const float* q  = (const float*)d_in[0];
  const float* k  = (const float*)d_in[1];
  const float* v  = (const float*)d_in[2];
  const float* Wq = (const float*)d_in[3];
  const float* bq = (const float*)d_in[4];
  const float* Wk = (const float*)d_in[5];
  const float* bk = (const float*)d_in[6];
  const float* Wv = (const float*)d_in[7];
  const float* bv = (const float*)d_in[8];
  const float* Wo = (const float*)d_in[9];
  const float* bo = (const float*)d_in[10];

  bf16_t* ws  = (bf16_t*)d_ws;
  bf16_t* qB  = ws;
  bf16_t* kB  = qB + bnd;
  bf16_t* vB  = kB + bnd;
  bf16_t* WqB = vB + bnd;
  bf16_t* WkB = WqB + ddl;
  bf16_t* WvB = WkB + ddl;
  bf16_t* WoB = WvB + ddl;
  bf16_t* qpB = WoB + ddl;
  bf16_t* kpB = qpB + bnd;
  bf16_t* vpB = kpB + bnd;
  bf16_t* vpT = vpB + bnd;
  bf16_t* S   = vpT + bnd;
  bf16_t* yT  = S + (long)b * nn;
  const size_t need = (size_t)(8 * bnd + 4 * ddl + (long)b * nn) * 2;
  if (ws_size < need) return;

  dim3 blk(256);

  // fp32 -> bf16 converts: ONE launch, 7 segments
  CvtArgs ca;
  ca.src[0] = q;  ca.dst[0] = qB;  ca.n4[0] = bnd / 4;
  ca.src[1] = k;  ca.dst[1] = kB;  ca.n4[1] = bnd / 4;
  ca.src[2] = v;  ca.dst[2] = vB;  ca.n4[2] = bnd / 4;
  ca.src[3] = Wq; ca.dst[3] = WqB; ca.n4[3] = ddl / 4;
  ca.src[4] = Wk; ca.dst[4] = WkB; ca.n4[4] = ddl / 4;
  ca.src[5] = Wv; ca.dst[5] = WvB; ca.n4[5] = ddl / 4;
  ca.src[6] = Wo; ca.dst[6] = WoB; ca.n4[6] = ddl / 4;
  cvt_all<<<dim3(512, 7), blk, 0, stream>>>(ca);

  // fused QKV projections: one dispatch, grid (8, 64, 3) = 1536 blocks
  QkvArgs qa;
  qa.A[0] = qB; qa.B[0] = WqB; qa.bias[0] = bq; qa.C[0] = qpB;
  qa.A[1] = kB; qa.B[1] = WkB; qa.bias[1] = bk; qa.C[1] = kpB;
  qa.A[2] = vB; qa.B[2] = WvB; qa.bias[2] = bv; qa.C[2] = vpB;
  gemm_qkv<<<dim3(d / 128, bn / 128, 3), blk, 0, stream>>>(qa, d, d);

  // vpT[z] = vpB[z]^T
  transpose_bf16<<<dim3(d / 32, n / 32, b), blk, 0, stream>>>(vpB, vpT, n, d, nd, nd);

  // scores: S[z] = qp[z] x kp[z]^T * (1/32), causal tile-skip
  gemm_bt<true, false, true, false><<<dim3(n / 128, n / 128, b), blk, 0, stream>>>(
      qpB, kpB, nullptr, S, n, d, 0.03125f, nd, nd, nn, 2);

  // causal softmax in place
  softmax_causal<<<dim3(n, b), blk, 0, stream>>>(S, n, nn);

  // yT[z] = vpT[z] x P[z]^T   (K bounded per N-tile by causality)
  gemm_bt<true, false, false, true><<<dim3(n / 128, d / 128, b), blk, 0, stream>>>(
      vpT, S, nullptr, yT, n, n, 1.f, nd, nn, nd, 2);

  // out = y2 x Wo^T + bo ; y2 flat == yT flat, fp32 out
  gemm_bt<false, true, false, false><<<dim3(d / 128, bn / 128, 1), blk, 0, stream>>>(
      yT, WoB, bo, (float*)d_out, d, d, 1.f, 0, 0, 0, 4);
}

// Round 3
// 221.870 us; speedup vs baseline: 1.2681x; 1.1512x over previous
//
#include <hip/hip_runtime.h>
#include <hip/hip_bf16.h>
#include <stdint.h>

typedef __bf16 bf16_t;
typedef __bf16 bf16x8 __attribute__((ext_vector_type(8)));
typedef __bf16 bf16x4 __attribute__((ext_vector_type(4)));
typedef float f32x4 __attribute__((ext_vector_type(4)));

#define GLD_LDS16(src, dst)                                                              \
  __builtin_amdgcn_global_load_lds((const __attribute__((address_space(1))) void*)(src), \
                                   (__attribute__((address_space(3))) void*)(dst), 16, 0, 0)

// ---------------------------------------------------------------------------
// fp32 -> bf16 convert, ALL tensors in one launch. blockIdx.y = segment.
// ---------------------------------------------------------------------------
struct CvtArgs {
  const float* src[7];
  bf16_t* dst[7];
  long n4[7];
};

__global__ __launch_bounds__(256) void cvt_all(CvtArgs a) {
  const int seg = blockIdx.y;
  const float* __restrict__ in = a.src[seg];
  bf16_t* __restrict__ out = a.dst[seg];
  const long n4 = a.n4[seg];
  long i = (long)blockIdx.x * blockDim.x + threadIdx.x;
  const long stride = (long)gridDim.x * blockDim.x;
  for (; i < n4; i += stride) {
    float4 v = ((const float4*)in)[i];
    bf16x4 o;
    o[0] = (bf16_t)v.x; o[1] = (bf16_t)v.y; o[2] = (bf16_t)v.z; o[3] = (bf16_t)v.w;
    ((bf16x4*)out)[i] = o;
  }
}

// ---------------------------------------------------------------------------
// bf16 transpose [rows,cols] -> [cols,rows], 32x32 LDS tiles, batched (z)
// ---------------------------------------------------------------------------
__global__ __launch_bounds__(256) void transpose_bf16(const bf16_t* __restrict__ in,
                                                      bf16_t* __restrict__ out,
                                                      int rows, int cols, long sIn, long sOut) {
  __shared__ bf16_t tile[32][33];
  const int z = blockIdx.z;
  in  += (long)z * sIn;
  out += (long)z * sOut;
  const int c0 = blockIdx.x << 5, r0 = blockIdx.y << 5;
  const int tc = threadIdx.x & 31, tr = threadIdx.x >> 5;
#pragma unroll
  for (int it = 0; it < 4; ++it)
    tile[tr + it * 8][tc] = in[(long)(r0 + tr + it * 8) * cols + c0 + tc];
  __syncthreads();
#pragma unroll
  for (int it = 0; it < 4; ++it)
    out[(long)(c0 + tr + it * 8) * rows + r0 + tc] = tile[tc][tr + it * 8];
}

// ---------------------------------------------------------------------------
// Causal row softmax, in-place on bf16 scores. One 256-thread block per row.
// Vectorized: each thread owns 8 CONTIGUOUS elements (bf16x8, 16B/lane).
// ---------------------------------------------------------------------------
__global__ __launch_bounds__(256) void softmax_causal(bf16_t* __restrict__ S, int n, long sB) {
  const int i = blockIdx.x;
  const int z = blockIdx.y;
  bf16_t* row = S + (long)z * sB + (long)i * n;
  const int t = threadIdx.x;
  const int j0 = t << 3;

  bf16x8 vv = ((const bf16x8*)row)[t];
  float vals[8];
  float mx = -3.0e38f;
#pragma unroll
  for (int e = 0; e < 8; ++e) {
    float v = (j0 + e <= i) ? (float)vv[e] : -3.0e38f;
    vals[e] = v;
    mx = fmaxf(mx, v);
  }
#pragma unroll
  for (int off = 32; off; off >>= 1) mx = fmaxf(mx, __shfl_xor(mx, off));
  __shared__ float redm[4];
  if ((t & 63) == 0) redm[t >> 6] = mx;
  __syncthreads();
  mx = fmaxf(fmaxf(redm[0], redm[1]), fmaxf(redm[2], redm[3]));

  float sum = 0.f;
#pragma unroll
  for (int e = 0; e < 8; ++e) {
    float p = (j0 + e <= i) ? __expf(vals[e] - mx) : 0.f;
    vals[e] = p;
    sum += p;
  }
#pragma unroll
  for (int off = 32; off; off >>= 1) sum += __shfl_xor(sum, off);
  __shared__ float reds[4];
  if ((t & 63) == 0) reds[t >> 6] = sum;
  __syncthreads();
  sum = reds[0] + reds[1] + reds[2] + reds[3];
  const float inv = 1.0f / sum;

  bf16x8 o;
#pragma unroll
  for (int e = 0; e < 8; ++e) o[e] = (bf16_t)(vals[e] * inv);
  ((bf16x8*)row)[t] = o;
}

// ---------------------------------------------------------------------------
// GEMM body: C[M,N] = alpha * A[M,K] * B[N,K]^T (+ bias[N]).
// m97 structure: 128x128 tile, BK=32, 256 threads = 4 waves (2x2 of 64x64),
// global_load_lds width 16, mfma_f32_16x16x32_bf16, fp32 accum.
// ---------------------------------------------------------------------------
template <bool BF16_OUT, bool BIAS, bool KBOUND>
__device__ __forceinline__ void gemm_body(const bf16_t* __restrict__ A,
                                          const bf16_t* __restrict__ B,
                                          const float* __restrict__ bias,
                                          void* __restrict__ Cout,
                                          int N, int K, float alpha,
                                          int m0, int n0) {
  int KT = K >> 5;
  if (KBOUND) {
    int kb = (n0 + 128) >> 5;
    if (kb < KT) KT = kb;
  }

  __shared__ __align__(16) bf16_t As[128 * 32];
  __shared__ __align__(16) bf16_t Bs[128 * 32];

  const int t = threadIdx.x;
  const int l = t & 63;
  const int w = t >> 6;
  const int wr = w >> 1, wc = w & 1;

  const int c0 = t, c1 = t + 256;
  const bf16_t* a_src0 = A + (long)(m0 + (c0 >> 2)) * K + ((c0 & 3) << 3);
  const bf16_t* a_src1 = A + (long)(m0 + (c1 >> 2)) * K + ((c1 & 3) << 3);
  const bf16_t* b_src0 = B + (long)(n0 + (c0 >> 2)) * K + ((c0 & 3) << 3);
  const bf16_t* b_src1 = B + (long)(n0 + (c1 >> 2)) * K + ((c1 & 3) << 3);
  char* const asb = (char*)As;
  char* const bsb = (char*)Bs;
  char* const a_dst0 = asb + w * 1024;
  char* const a_dst1 = asb + 4096 + w * 1024;
  char* const b_dst0 = bsb + w * 1024;
  char* const b_dst1 = bsb + 4096 + w * 1024;

  const int r16 = l & 15, kg = l >> 4;
  int aoff[4], boff[4];
#pragma unroll
  for (int mi = 0; mi < 4; ++mi) aoff[mi] = (((wr * 64 + mi * 16 + r16) * 32) + kg * 8) * 2;
#pragma unroll
  for (int ni = 0; ni < 4; ++ni) boff[ni] = (((wc * 64 + ni * 16 + r16) * 32) + kg * 8) * 2;

  f32x4 acc[4][4] = {};

  for (int kt = 0; kt < KT; ++kt) {
    __syncthreads();
    GLD_LDS16(a_src0, a_dst0);
    GLD_LDS16(a_src1, a_dst1);
    GLD_LDS16(b_src0, b_dst0);
    GLD_LDS16(b_src1, b_dst1);
    a_src0 += 32; a_src1 += 32; b_src0 += 32; b_src1 += 32;
    __syncthreads();

    bf16x8 af[4], bfr[4];
#pragma unroll
    for (int mi = 0; mi < 4; ++mi) af[mi] = *(const bf16x8*)(asb + aoff[mi]);
#pragma unroll
    for (int ni = 0; ni < 4; ++ni) bfr[ni] = *(const bf16x8*)(bsb + boff[ni]);
#pragma unroll
    for (int mi = 0; mi < 4; ++mi)
#pragma unroll
      for (int ni = 0; ni < 4; ++ni)
        acc[mi][ni] = __builtin_amdgcn_mfma_f32_16x16x32_bf16(af[mi], bfr[ni], acc[mi][ni], 0, 0, 0);
  }

  const int rowbase = m0 + wr * 64 + ((l >> 4) << 2);
  const int colbase = n0 + wc * 64 + (l & 15);
  if constexpr (BF16_OUT) {
    bf16_t* C = (bf16_t*)Cout;
#pragma unroll
    for (int mi = 0; mi < 4; ++mi)
#pragma unroll
      for (int ni = 0; ni < 4; ++ni) {
        const int col = colbase + ni * 16;
        float badd = 0.f;
        if constexpr (BIAS) badd = bias[col];
#pragma unroll
        for (int j = 0; j < 4; ++j) {
          float v = acc[mi][ni][j] * alpha + badd;
          C[(long)(rowbase + mi * 16 + j) * N + col] = (bf16_t)v;
        }
      }
  } else {
    float* C = (float*)Cout;
#pragma unroll
    for (int mi = 0; mi < 4; ++mi)
#pragma unroll
      for (int ni = 0; ni < 4; ++ni) {
        const int col = colbase + ni * 16;
        float badd = 0.f;
        if constexpr (BIAS) badd = bias[col];
#pragma unroll
        for (int j = 0; j < 4; ++j) {
          float v = acc[mi][ni][j] * alpha + badd;
          C[(long)(rowbase + mi * 16 + j) * N + col] = v;
        }
      }
  }
}

// XCD-chunked bijective remap of the flattened block id. REQUIRES nwg % 8 == 0
// (all launches below satisfy this). Hardware round-robins linear ids across
// the 8 XCDs; after remap, logical tiles 0..cpx-1 land on XCD 0, etc., so
// consecutive logical tiles (x-fastest: same A-panel) share one L2.
__device__ __forceinline__ void xcd_remap(int& bx, int& by, int& bz) {
  const int gx = gridDim.x, gy = gridDim.y;
  int lin = (blockIdx.z * gy + blockIdx.y) * gx + blockIdx.x;
  const int nwg = gx * gy * (int)gridDim.z;
  lin = (lin & 7) * (nwg >> 3) + (lin >> 3);
  bx = lin % gx;
  const int rem = lin / gx;
  by = rem % gy;
  bz = rem / gy;
}

// z = batch index with element strides (scores / PV / out-proj)
template <bool BF16_OUT, bool BIAS, bool CAUSAL_SKIP, bool KBOUND>
__global__ __launch_bounds__(256, 4) void gemm_bt(const bf16_t* __restrict__ A,
                                                  const bf16_t* __restrict__ B,
                                                  const float* __restrict__ bias,
                                                  void* __restrict__ Cout,
                                                  int N, int K, float alpha,
                                                  long sAb, long sBb, long sCb, int eltC) {
  int bx, by, bz;
  xcd_remap(bx, by, bz);
  const int m0 = by << 7, n0 = bx << 7;
  if (CAUSAL_SKIP && n0 > m0 + 127) return;
  gemm_body<BF16_OUT, BIAS, KBOUND>(A + (long)bz * sAb, B + (long)bz * sBb, bias,
                                    (char*)Cout + (long)bz * sCb * eltC, N, K, alpha, m0, n0);
}

// z = operation index selecting from pointer arrays (fused QKV projections)
struct QkvArgs {
  const bf16_t* A[3];
  const bf16_t* B[3];
  const float* bias[3];
  bf16_t* C[3];
};

__global__ __launch_bounds__(256, 4) void gemm_qkv(QkvArgs a, int N, int K) {
  int bx, by, bz;
  xcd_remap(bx, by, bz);
  gemm_body<true, true, false>(a.A[bz], a.B[bz], a.bias[bz], a.C[bz], N, K, 1.0f,
                               by << 7, bx << 7);
}

// ---------------------------------------------------------------------------
extern "C" void kernel_launch(void* const* d_in, const int* in_sizes, int n_in,
                              void* d_out, int out_size, void* d_ws, size_t ws_size,
                              hipStream_t stream) {
  const int b = 4, n = 2048, d = 1024;
  const long nd  = (long)n * d;
  const long bn  = (long)b * n;
  const long bnd = bn * d;
  const long ddl = (long)d * d;
  const long nn  = (long)n * n;

  const float* q  = (const float*)d_in[0];
  const float* k  = (const float*)d_in[1];
  const float* v  = (const float*)d_in[2];
  const float* Wq = (const float*)d_in[3];
  const float* bq = (const float*)d_in[4];
  const float* Wk = (const float*)d_in[5];
  const float* bk = (const float*)d_in[6];
  const float* Wv = (const float*)d_in[7];
  const float* bv = (const float*)d_in[8];
  const float* Wo = (const float*)d_in[9];
  const float* bo = (const float*)d_in[10];

  bf16_t* ws  = (bf16_t*)d_ws;
  bf16_t* qB  = ws;
  bf16_t* kB  = qB + bnd;
  bf16_t* vB  = kB + bnd;
  bf16_t* WqB = vB + bnd;
  bf16_t* WkB = WqB + ddl;
  bf16_t* WvB = WkB + ddl;
  bf16_t* WoB = WvB + ddl;
  bf16_t* qpB = WoB + ddl;
  bf16_t* kpB = qpB + bnd;
  bf16_t* vpB = kpB + bnd;
  bf16_t* vpT = vpB + bnd;
  bf16_t* S   = vpT + bnd;
  bf16_t* yT  = S + (long)b * nn;
  const size_t need = (size_t)(8 * bnd + 4 * ddl + (long)b * nn) * 2;
  if (ws_size < need) return;

  dim3 blk(256);

  // fp32 -> bf16 converts: ONE launch, 7 segments
  CvtArgs ca;
  ca.src[0] = q;  ca.dst[0] = qB;  ca.n4[0] = bnd / 4;
  ca.src[1] = k;  ca.dst[1] = kB;  ca.n4[1] = bnd / 4;
  ca.src[2] = v;  ca.dst[2] = vB;  ca.n4[2] = bnd / 4;
  ca.src[3] = Wq; ca.dst[3] = WqB; ca.n4[3] = ddl / 4;
  ca.src[4] = Wk; ca.dst[4] = WkB; ca.n4[4] = ddl / 4;
  ca.src[5] = Wv; ca.dst[5] = WvB; ca.n4[5] = ddl / 4;
  ca.src[6] = Wo; ca.dst[6] = WoB; ca.n4[6] = ddl / 4;
  cvt_all<<<dim3(512, 7), blk, 0, stream>>>(ca);

  // fused QKV projections: one dispatch, grid (8, 64, 3) = 1536 blocks
  QkvArgs qa;
  qa.A[0] = qB; qa.B[0] = WqB; qa.bias[0] = bq; qa.C[0] = qpB;
  qa.A[1] = kB; qa.B[1] = WkB; qa.bias[1] = bk; qa.C[1] = kpB;
  qa.A[2] = vB; qa.B[2] = WvB; qa.bias[2] = bv; qa.C[2] = vpB;
  gemm_qkv<<<dim3(d / 128, bn / 128, 3), blk, 0, stream>>>(qa, d, d);

  // vpT[z] = vpB[z]^T
  transpose_bf16<<<dim3(d / 32, n / 32, b), blk, 0, stream>>>(vpB, vpT, n, d, nd, nd);

  // scores: S[z] = qp[z] x kp[z]^T * (1/32), causal tile-skip
  gemm_bt<true, false, true, false><<<dim3(n / 128, n / 128, b), blk, 0, stream>>>(
      qpB, kpB, nullptr, S, n, d, 0.03125f, nd, nd, nn, 2);

  // causal softmax in place
  softmax_causal<<<dim3(n, b), blk, 0, stream>>>(S, n, nn);

  // yT[z] = vpT[z] x P[z]^T   (K bounded per N-tile by causality)
  gemm_bt<true, false, false, true><<<dim3(n / 128, d / 128, b), blk, 0, stream>>>(
      vpT, S, nullptr, yT, n, n, 1.f, nd, nn, nd, 2);

  // out = y2 x Wo^T + bo ; y2 flat == yT flat, fp32 out
  gemm_bt<false, true, false, false><<<dim3(d / 128, bn / 128, 1), blk, 0, stream>>>(
      yT, WoB, bo, (float*)d_out, d, d, 1.f, 0, 0, 0, 4);
}

// Round 4
// 220.888 us; speedup vs baseline: 1.2737x; 1.0044x over previous
//
#include <hip/hip_runtime.h>
#include <hip/hip_bf16.h>
#include <stdint.h>

typedef __bf16 bf16_t;
typedef __bf16 bf16x8 __attribute__((ext_vector_type(8)));
typedef __bf16 bf16x4 __attribute__((ext_vector_type(4)));
typedef float f32x4 __attribute__((ext_vector_type(4)));

#define GLD_LDS16(src, dst)                                                              \
  __builtin_amdgcn_global_load_lds((const __attribute__((address_space(1))) void*)(src), \
                                   (__attribute__((address_space(3))) void*)(dst), 16, 0, 0)

#define BAR() __builtin_amdgcn_s_barrier()
#define LGKM0() asm volatile("s_waitcnt lgkmcnt(0)" ::: "memory")
#define VMC6() asm volatile("s_waitcnt vmcnt(6)" ::: "memory")
#define VMC0() asm volatile("s_waitcnt vmcnt(0)" ::: "memory")

// st_16x32 swizzle: XOR byte-bit-5 with bit-9 (within each half's 16KB region,
// layout = [8 rowgrp][2 colgrp][16 rows][32 cols] bf16; bit9 == (row&8)).
__device__ __forceinline__ int swz(int x) { return x ^ (((x >> 9) & 1) << 5); }

// ---------------------------------------------------------------------------
// fp32 -> bf16 convert, ALL tensors in one launch. blockIdx.y = segment.
// ---------------------------------------------------------------------------
struct CvtArgs {
  const float* src[7];
  bf16_t* dst[7];
  long n4[7];
};

__global__ __launch_bounds__(256) void cvt_all(CvtArgs a) {
  const int seg = blockIdx.y;
  const float* __restrict__ in = a.src[seg];
  bf16_t* __restrict__ out = a.dst[seg];
  const long n4 = a.n4[seg];
  long i = (long)blockIdx.x * blockDim.x + threadIdx.x;
  const long stride = (long)gridDim.x * blockDim.x;
  for (; i < n4; i += stride) {
    float4 v = ((const float4*)in)[i];
    bf16x4 o;
    o[0] = (bf16_t)v.x; o[1] = (bf16_t)v.y; o[2] = (bf16_t)v.z; o[3] = (bf16_t)v.w;
    ((bf16x4*)out)[i] = o;
  }
}

// ---------------------------------------------------------------------------
// Causal row softmax, in-place on bf16 scores. One 256-thread block per row.
// ---------------------------------------------------------------------------
__global__ __launch_bounds__(256) void softmax_causal(bf16_t* __restrict__ S, int n, long sB) {
  const int i = blockIdx.x;
  const int z = blockIdx.y;
  bf16_t* row = S + (long)z * sB + (long)i * n;
  const int t = threadIdx.x;
  const int j0 = t << 3;

  bf16x8 vv = ((const bf16x8*)row)[t];
  float vals[8];
  float mx = -3.0e38f;
#pragma unroll
  for (int e = 0; e < 8; ++e) {
    float v = (j0 + e <= i) ? (float)vv[e] : -3.0e38f;
    vals[e] = v;
    mx = fmaxf(mx, v);
  }
#pragma unroll
  for (int off = 32; off; off >>= 1) mx = fmaxf(mx, __shfl_xor(mx, off));
  __shared__ float redm[4];
  if ((t & 63) == 0) redm[t >> 6] = mx;
  __syncthreads();
  mx = fmaxf(fmaxf(redm[0], redm[1]), fmaxf(redm[2], redm[3]));

  float sum = 0.f;
#pragma unroll
  for (int e = 0; e < 8; ++e) {
    float p = (j0 + e <= i) ? __expf(vals[e] - mx) : 0.f;
    vals[e] = p;
    sum += p;
  }
#pragma unroll
  for (int off = 32; off; off >>= 1) sum += __shfl_xor(sum, off);
  __shared__ float reds[4];
  if ((t & 63) == 0) reds[t >> 6] = sum;
  __syncthreads();
  sum = reds[0] + reds[1] + reds[2] + reds[3];
  const float inv = 1.0f / sum;

  bf16x8 o;
#pragma unroll
  for (int e = 0; e < 8; ++e) o[e] = (bf16_t)(vals[e] * inv);
  ((bf16x8*)row)[t] = o;
}

// ---------------------------------------------------------------------------
// XCD-chunked bijective remap (requires nwg % 8 == 0; all grids comply).
// ---------------------------------------------------------------------------
__device__ __forceinline__ void xcd_remap(int& bx, int& by, int& bz) {
  const int gx = gridDim.x, gy = gridDim.y;
  int lin = (blockIdx.z * gy + blockIdx.y) * gx + blockIdx.x;
  const int nwg = gx * gy * (int)gridDim.z;
  lin = (lin & 7) * (nwg >> 3) + (lin >> 3);
  bx = lin % gx;
  const int rem = lin / gx;
  by = rem % gy;
  bz = rem / gy;
}

// ===========================================================================
// 8-phase 256x256 GEMM (BK=64, 512 thr = 8 waves as 2x4 per 128x128 quadrant).
// C[M,N] = A[M,K] x B[N,K]^T. K = 1024 fixed (NT = 16, even).
// LDS 128 KiB: A halves at buf*32768 + half*16384; B at +65536.
// Swizzled subtiled layout, staged via pre-permuted global src (linear dest).
// Schedule invariants (derived; see analysis): one half staged per phase into
// the region whose last ds_read was >=1 phase prior; vmcnt(6) at P4/P8 secures
// the next K-tile's 4 halves with 3 halves (6 loads) left in flight.
// MODE 0: fused QKV (z = op; bias; z==2 writes transposed into vpT[b][d][n]).
// MODE 1: scores (z = batch; alpha=1/32; causal tile skip).
// ===========================================================================
struct G8Args {
  const bf16_t* A[3];
  const bf16_t* W[3];
  const float* bias[3];
  bf16_t* C[3];
  long sA, sB, sC;
};

template <int HALF, int BUF>
__device__ __forceinline__ void stage8(char* lds, const bf16_t* srcH, const int (&soff)[2],
                                       int wid, int tile) {
  const bf16_t* s = srcH + tile * 64;
  char* d = lds + (HALF >= 2 ? 65536 : 0) + BUF * 32768 + (HALF & 1) * 16384 + wid * 2048;
  GLD_LDS16(s + soff[0], d);
  GLD_LDS16(s + soff[1], d + 1024);
}

template <int BUF, int QM>
__device__ __forceinline__ void rdA(char* lds, const int (&aoffp)[4][2], bf16x8 (&af)[4][2]) {
  char* b = lds + BUF * 32768 + QM * 16384;
#pragma unroll
  for (int mi = 0; mi < 4; ++mi)
#pragma unroll
    for (int kk = 0; kk < 2; ++kk) af[mi][kk] = *(const bf16x8*)(b + aoffp[mi][kk]);
}

template <int BUF, int QN>
__device__ __forceinline__ void rdB(char* lds, const int (&boffp)[2][2], bf16x8 (&bf)[2][2]) {
  char* b = lds + 65536 + BUF * 32768 + QN * 16384;
#pragma unroll
  for (int ni = 0; ni < 2; ++ni)
#pragma unroll
    for (int kk = 0; kk < 2; ++kk) bf[ni][kk] = *(const bf16x8*)(b + boffp[ni][kk]);
}

template <int QM, int QN>
__device__ __forceinline__ void mm16(f32x4 (&acc)[2][2][4][2], const bf16x8 (&af)[4][2],
                                     const bf16x8 (&bf)[2][2]) {
  __builtin_amdgcn_s_setprio(1);
#pragma unroll
  for (int mi = 0; mi < 4; ++mi)
#pragma unroll
    for (int ni = 0; ni < 2; ++ni)
#pragma unroll
      for (int kk = 0; kk < 2; ++kk)
        acc[QM][QN][mi][ni] = __builtin_amdgcn_mfma_f32_16x16x32_bf16(
            af[mi][kk], bf[ni][kk], acc[QM][QN][mi][ni], 0, 0, 0);
  __builtin_amdgcn_s_setprio(0);
}

template <int MODE>
__global__ __launch_bounds__(512, 2) void gemm8(G8Args ga) {
  int bx, by, bz;
  xcd_remap(bx, by, bz);
  const int m0 = by << 8, n0 = bx << 8;
  if (MODE == 1 && n0 > m0 + 255) return;  // uniform block exit, pre-barrier

  const int K = 1024, NT = 16;
  const bf16_t* A;
  const bf16_t* B;
  const float* bias = nullptr;
  if (MODE == 0) {
    A = ga.A[bz]; B = ga.W[bz]; bias = ga.bias[bz];
  } else {
    A = ga.A[0] + (long)bz * ga.sA;
    B = ga.W[0] + (long)bz * ga.sB;
  }

  __shared__ __align__(16) char lds[131072];

  const int t = threadIdx.x;
  const int wid = t >> 6, l = t & 63;
  const int wm = wid >> 2, wn = wid & 3;
  const int ri16 = l & 15, kg = l >> 4;

  // ---- staging source offsets: invert (subtiled+swizzled layout) so the
  // linear gload_lds dest chunk ch receives the element that belongs there.
  int soff[2];
#pragma unroll
  for (int i = 0; i < 2; ++i) {
    const int sub = wid * 2 + i;              // 16B-chunk group = sub*64 + lane
    const int ri = l >> 2;                    // row within 16-row subtile
    const int cq = (l & 3) ^ ((ri & 8) >> 2); // 8-elem col chunk (swizzle inverse)
    const int r = (sub >> 1) * 16 + ri;       // row within 128-row half
    const int c = (sub & 1) * 32 + cq * 8;    // col within 64
    soff[i] = r * K + c;
  }
  const bf16_t* srcA0 = A + (long)m0 * K;
  const bf16_t* srcA1 = A + (long)(m0 + 128) * K;
  const bf16_t* srcB0 = B + (long)n0 * K;
  const bf16_t* srcB1 = B + (long)(n0 + 128) * K;

  // ---- fragment ds_read byte offsets (within a 16KB half region)
  int aoffp[4][2], boffp[2][2];
#pragma unroll
  for (int mi = 0; mi < 4; ++mi)
#pragma unroll
    for (int kk = 0; kk < 2; ++kk)
      aoffp[mi][kk] = swz((wm * 4 + mi) * 2048 + kk * 1024 + ri16 * 64 + kg * 16);
#pragma unroll
  for (int ni = 0; ni < 2; ++ni)
#pragma unroll
    for (int kk = 0; kk < 2; ++kk)
      boffp[ni][kk] = swz((wn * 2 + ni) * 2048 + kk * 1024 + ri16 * 64 + kg * 16);

  f32x4 acc[2][2][4][2] = {};
  bf16x8 af[4][2], bf0[2][2], bf1[2][2];

  // ---- prologue: t0 all 4 halves, then t1's A0,B0,B1 (A1(t1) issues at P1)
  stage8<0, 0>(lds, srcA0, soff, wid, 0);
  stage8<2, 0>(lds, srcB0, soff, wid, 0);
  stage8<3, 0>(lds, srcB1, soff, wid, 0);
  stage8<1, 0>(lds, srcA1, soff, wid, 0);
  stage8<0, 1>(lds, srcA0, soff, wid, 1);
  stage8<2, 1>(lds, srcB0, soff, wid, 1);
  stage8<3, 1>(lds, srcB1, soff, wid, 1);
  VMC6();  // t0's 8 loads done; t1's 6 in flight
  BAR();

  for (int tt = 0; tt < NT; tt += 2) {
    const bool hasNext = (tt + 2) < NT;
    // P1: Q(0,0) buf0 | issue A1(tt+1)->buf1 (region free since prev P7)
    rdA<0, 0>(lds, aoffp, af);
    rdB<0, 0>(lds, boffp, bf0);
    stage8<1, 1>(lds, srcA1, soff, wid, tt + 1);
    BAR(); LGKM0();
    mm16<0, 0>(acc, af, bf0);
    BAR();
    // P2: Q(0,1) | issue A0(tt+2)->buf0 (A0 last read P1)
    rdB<0, 1>(lds, boffp, bf1);
    if (hasNext) stage8<0, 0>(lds, srcA0, soff, wid, tt + 2);
    BAR(); LGKM0();
    mm16<0, 1>(acc, af, bf1);
    BAR();
    // P3: Q(1,0) | issue B0(tt+2)->buf0 (B0 last read P1)
    rdA<0, 1>(lds, aoffp, af);
    if (hasNext) stage8<2, 0>(lds, srcB0, soff, wid, tt + 2);
    BAR(); LGKM0();
    mm16<1, 0>(acc, af, bf0);
    BAR();
    // P4: Q(1,1) | issue B1(tt+2)->buf0 (B1 last read P2) | K-tile boundary
    if (hasNext) stage8<3, 0>(lds, srcB1, soff, wid, tt + 2);
    BAR(); LGKM0();
    mm16<1, 1>(acc, af, bf1);
    if (hasNext) { VMC6(); } else { VMC0(); }  // secure tile tt+1 (all 4 halves)
    BAR();
    // P5: Q(0,0) buf1 (tile tt+1) | issue A1(tt+2)->buf0 (A1 last read P3)
    rdA<1, 0>(lds, aoffp, af);
    rdB<1, 0>(lds, boffp, bf0);
    if (hasNext) stage8<1, 0>(lds, srcA1, soff, wid, tt + 2);
    BAR(); LGKM0();
    mm16<0, 0>(acc, af, bf0);
    BAR();
    // P6: Q(0,1) | issue A0(tt+3)->buf1 (A0 last read P5)
    rdB<1, 1>(lds, boffp, bf1);
    if (hasNext) stage8<0, 1>(lds, srcA0, soff, wid, tt + 3);
    BAR(); LGKM0();
    mm16<0, 1>(acc, af, bf1);
    BAR();
    // P7: Q(1,0) | issue B0(tt+3)->buf1
    rdA<1, 1>(lds, aoffp, af);
    if (hasNext) stage8<2, 1>(lds, srcB0, soff, wid, tt + 3);
    BAR(); LGKM0();
    mm16<1, 0>(acc, af, bf0);
    BAR();
    // P8: Q(1,1) | issue B1(tt+3)->buf1 | K-tile boundary
    if (hasNext) stage8<3, 1>(lds, srcB1, soff, wid, tt + 3);
    BAR(); LGKM0();
    mm16<1, 1>(acc, af, bf1);
    if (hasNext) { VMC6(); }  // secure tile tt+2; 3 halves of tt+3 in flight
    BAR();
  }

  // ---- epilogue: C row = m0+qm*128+wm*64+mi*16+kg*4+j; col = n0+qn*128+wn*32+ni*16+ri16
  if (MODE == 0) {
    if (bz < 2) {
      bf16_t* C = ga.C[bz];  // [8192,1024]
#pragma unroll
      for (int qm = 0; qm < 2; ++qm)
#pragma unroll
        for (int qn = 0; qn < 2; ++qn)
#pragma unroll
          for (int mi = 0; mi < 4; ++mi)
#pragma unroll
            for (int ni = 0; ni < 2; ++ni) {
              const int col = n0 + qn * 128 + wn * 32 + ni * 16 + ri16;
              const int row0 = m0 + qm * 128 + wm * 64 + mi * 16 + kg * 4;
              const float badd = bias[col];
#pragma unroll
              for (int j = 0; j < 4; ++j)
                C[(long)(row0 + j) * 1024 + col] = (bf16_t)(acc[qm][qn][mi][ni][j] + badd);
            }
    } else {
      bf16_t* C = ga.C[2];  // vpT: per-batch [1024][2048]
#pragma unroll
      for (int qm = 0; qm < 2; ++qm)
#pragma unroll
        for (int qn = 0; qn < 2; ++qn)
#pragma unroll
          for (int mi = 0; mi < 4; ++mi)
#pragma unroll
            for (int ni = 0; ni < 2; ++ni) {
              const int col = n0 + qn * 128 + wn * 32 + ni * 16 + ri16;
              const int row0 = m0 + qm * 128 + wm * 64 + mi * 16 + kg * 4;
              const float badd = bias[col];
              const int batch = row0 >> 11, nr = row0 & 2047;
              bf16x4 o;
#pragma unroll
              for (int j = 0; j < 4; ++j) o[j] = (bf16_t)(acc[qm][qn][mi][ni][j] + badd);
              *(bf16x4*)(C + (long)batch * (2048 * 1024) + (long)col * 2048 + nr) = o;
            }
    }
  } else {
    bf16_t* C = ga.C[0] + (long)bz * ga.sC;  // S[z]: [2048,2048]
#pragma unroll
    for (int qm = 0; qm < 2; ++qm)
#pragma unroll
      for (int qn = 0; qn < 2; ++qn)
#pragma unroll
        for (int mi = 0; mi < 4; ++mi)
#pragma unroll
          for (int ni = 0; ni < 2; ++ni) {
            const int col = n0 + qn * 128 + wn * 32 + ni * 16 + ri16;
            const int row0 = m0 + qm * 128 + wm * 64 + mi * 16 + kg * 4;
#pragma unroll
            for (int j = 0; j < 4; ++j)
              C[(long)(row0 + j) * 2048 + col] = (bf16_t)(acc[qm][qn][mi][ni][j] * 0.03125f);
          }
  }
}

// ---------------------------------------------------------------------------
// 128x128 m97-structure GEMM (kept for PV + out-proj; proven in R1-R3).
// ---------------------------------------------------------------------------
template <bool BF16_OUT, bool BIAS, bool KBOUND>
__device__ __forceinline__ void gemm_body(const bf16_t* __restrict__ A,
                                          const bf16_t* __restrict__ B,
                                          const float* __restrict__ bias,
                                          void* __restrict__ Cout,
                                          int N, int K, float alpha,
                                          int m0, int n0) {
  int KT = K >> 5;
  if (KBOUND) {
    int kb = (n0 + 128) >> 5;
    if (kb < KT) KT = kb;
  }

  __shared__ __align__(16) bf16_t As[128 * 32];
  __shared__ __align__(16) bf16_t Bs[128 * 32];

  const int t = threadIdx.x;
  const int l = t & 63;
  const int w = t >> 6;
  const int wr = w >> 1, wc = w & 1;

  const int c0 = t, c1 = t + 256;
  const bf16_t* a_src0 = A + (long)(m0 + (c0 >> 2)) * K + ((c0 & 3) << 3);
  const bf16_t* a_src1 = A + (long)(m0 + (c1 >> 2)) * K + ((c1 & 3) << 3);
  const bf16_t* b_src0 = B + (long)(n0 + (c0 >> 2)) * K + ((c0 & 3) << 3);
  const bf16_t* b_src1 = B + (long)(n0 + (c1 >> 2)) * K + ((c1 & 3) << 3);
  char* const asb = (char*)As;
  char* const bsb = (char*)Bs;
  char* const a_dst0 = asb + w * 1024;
  char* const a_dst1 = asb + 4096 + w * 1024;
  char* const b_dst0 = bsb + w * 1024;
  char* const b_dst1 = bsb + 4096 + w * 1024;

  const int r16 = l & 15, kg = l >> 4;
  int aoff[4], boff[4];
#pragma unroll
  for (int mi = 0; mi < 4; ++mi) aoff[mi] = (((wr * 64 + mi * 16 + r16) * 32) + kg * 8) * 2;
#pragma unroll
  for (int ni = 0; ni < 4; ++ni) boff[ni] = (((wc * 64 + ni * 16 + r16) * 32) + kg * 8) * 2;

  f32x4 acc[4][4] = {};

  for (int kt = 0; kt < KT; ++kt) {
    __syncthreads();
    GLD_LDS16(a_src0, a_dst0);
    GLD_LDS16(a_src1, a_dst1);
    GLD_LDS16(b_src0, b_dst0);
    GLD_LDS16(b_src1, b_dst1);
    a_src0 += 32; a_src1 += 32; b_src0 += 32; b_src1 += 32;
    __syncthreads();

    bf16x8 af[4], bfr[4];
#pragma unroll
    for (int mi = 0; mi < 4; ++mi) af[mi] = *(const bf16x8*)(asb + aoff[mi]);
#pragma unroll
    for (int ni = 0; ni < 4; ++ni) bfr[ni] = *(const bf16x8*)(bsb + boff[ni]);
#pragma unroll
    for (int mi = 0; mi < 4; ++mi)
#pragma unroll
      for (int ni = 0; ni < 4; ++ni)
        acc[mi][ni] = __builtin_amdgcn_mfma_f32_16x16x32_bf16(af[mi], bfr[ni], acc[mi][ni], 0, 0, 0);
  }

  const int rowbase = m0 + wr * 64 + ((l >> 4) << 2);
  const int colbase = n0 + wc * 64 + (l & 15);
  if constexpr (BF16_OUT) {
    bf16_t* C = (bf16_t*)Cout;
#pragma unroll
    for (int mi = 0; mi < 4; ++mi)
#pragma unroll
      for (int ni = 0; ni < 4; ++ni) {
        const int col = colbase + ni * 16;
        float badd = 0.f;
        if constexpr (BIAS) badd = bias[col];
#pragma unroll
        for (int j = 0; j < 4; ++j) {
          float v = acc[mi][ni][j] * alpha + badd;
          C[(long)(rowbase + mi * 16 + j) * N + col] = (bf16_t)v;
        }
      }
  } else {
    float* C = (float*)Cout;
#pragma unroll
    for (int mi = 0; mi < 4; ++mi)
#pragma unroll
      for (int ni = 0; ni < 4; ++ni) {
        const int col = colbase + ni * 16;
        float badd = 0.f;
        if constexpr (BIAS) badd = bias[col];
#pragma unroll
        for (int j = 0; j < 4; ++j) {
          float v = acc[mi][ni][j] * alpha + badd;
          C[(long)(rowbase + mi * 16 + j) * N + col] = v;
        }
      }
  }
}

template <bool BF16_OUT, bool BIAS, bool KBOUND>
__global__ __launch_bounds__(256, 4) void gemm_bt(const bf16_t* __restrict__ A,
                                                  const bf16_t* __restrict__ B,
                                                  const float* __restrict__ bias,
                                                  void* __restrict__ Cout,
                                                  int N, int K, float alpha,
                                                  long sAb, long sBb, long sCb, int eltC) {
  int bx, by, bz;
  xcd_remap(bx, by, bz);
  const int m0 = by << 7, n0 = bx << 7;
  gemm_body<BF16_OUT, BIAS, KBOUND>(A + (long)bz * sAb, B + (long)bz * sBb, bias,
                                    (char*)Cout + (long)bz * sCb * eltC, N, K, alpha, m0, n0);
}

// ---------------------------------------------------------------------------
extern "C" void kernel_launch(void* const* d_in, const int* in_sizes, int n_in,
                              void* d_out, int out_size, void* d_ws, size_t ws_size,
                              hipStream_t stream) {
  const int b = 4, n = 2048, d = 1024;
  const long nd  = (long)n * d;
  const long bn  = (long)b * n;
  const long bnd = bn * d;
  const long ddl = (long)d * d;
  const long nn  = (long)n * n;

  const float* q  = (const float*)d_in[0];
  const float* k  = (const float*)d_in[1];
  const float* v  = (const float*)d_in[2];
  const float* Wq = (const float*)d_in[3];
  const float* bq = (const float*)d_in[4];
  const float* Wk = (const float*)d_in[5];
  const float* bk = (const float*)d_in[6];
  const float* Wv = (const float*)d_in[7];
  const float* bv = (const float*)d_in[8];
  const float* Wo = (const float*)d_in[9];
  const float* bo = (const float*)d_in[10];

  bf16_t* ws  = (bf16_t*)d_ws;
  bf16_t* qB  = ws;
  bf16_t* kB  = qB + bnd;
  bf16_t* vB  = kB + bnd;
  bf16_t* WqB = vB + bnd;
  bf16_t* WkB = WqB + ddl;
  bf16_t* WvB = WkB + ddl;
  bf16_t* WoB = WvB + ddl;
  bf16_t* qpB = WoB + ddl;
  bf16_t* kpB = qpB + bnd;
  bf16_t* vpT = kpB + bnd;       // per-batch [d][n] (written by V-proj epilogue)
  bf16_t* S   = vpT + bnd;
  bf16_t* yT  = S + (long)b * nn;
  const size_t need = (size_t)(7 * bnd + 4 * ddl + (long)b * nn) * 2;
  if (ws_size < need) return;

  dim3 blk(256);

  // fp32 -> bf16 converts: ONE launch, 7 segments
  CvtArgs ca;
  ca.src[0] = q;  ca.dst[0] = qB;  ca.n4[0] = bnd / 4;
  ca.src[1] = k;  ca.dst[1] = kB;  ca.n4[1] = bnd / 4;
  ca.src[2] = v;  ca.dst[2] = vB;  ca.n4[2] = bnd / 4;
  ca.src[3] = Wq; ca.dst[3] = WqB; ca.n4[3] = ddl / 4;
  ca.src[4] = Wk; ca.dst[4] = WkB; ca.n4[4] = ddl / 4;
  ca.src[5] = Wv; ca.dst[5] = WvB; ca.n4[5] = ddl / 4;
  ca.src[6] = Wo; ca.dst[6] = WoB; ca.n4[6] = ddl / 4;
  cvt_all<<<dim3(512, 7), blk, 0, stream>>>(ca);

  // fused QKV projections, 8-phase 256^2 kernel: grid (4, 32, 3) = 384 blocks
  G8Args qa = {};
  qa.A[0] = qB; qa.W[0] = WqB; qa.bias[0] = bq; qa.C[0] = qpB;
  qa.A[1] = kB; qa.W[1] = WkB; qa.bias[1] = bk; qa.C[1] = kpB;
  qa.A[2] = vB; qa.W[2] = WvB; qa.bias[2] = bv; qa.C[2] = vpT;  // V writes transposed
  gemm8<0><<<dim3(d / 256, bn / 256, 3), dim3(512), 0, stream>>>(qa);

  // scores: S[z] = qp[z] x kp[z]^T * (1/32), 8-phase, causal tile-skip
  G8Args sa = {};
  sa.A[0] = qpB; sa.W[0] = kpB; sa.C[0] = S;
  sa.sA = nd; sa.sB = nd; sa.sC = nn;
  gemm8<1><<<dim3(n / 256, n / 256, b), dim3(512), 0, stream>>>(sa);

  // causal softmax in place
  softmax_causal<<<dim3(n, b), blk, 0, stream>>>(S, n, nn);

  // yT[z] = vpT[z] x P[z]^T   (128^2 kernel, K bounded per N-tile by causality)
  gemm_bt<true, false, true><<<dim3(n / 128, d / 128, b), blk, 0, stream>>>(
      vpT, S, nullptr, yT, n, n, 1.f, nd, nn, nd, 2);

  // out = y2 x Wo^T + bo ; y2 flat == yT flat, fp32 out
  gemm_bt<false, true, false><<<dim3(d / 128, bn / 128, 1), blk, 0, stream>>>(
      yT, WoB, bo, (float*)d_out, d, d, 1.f, 0, 0, 0, 4);
}

// Round 5
// 210.688 us; speedup vs baseline: 1.3354x; 1.0484x over previous
//
#include <hip/hip_runtime.h>
#include <hip/hip_bf16.h>
#include <stdint.h>

typedef __bf16 bf16_t;
typedef __bf16 bf16x8 __attribute__((ext_vector_type(8)));
typedef __bf16 bf16x4 __attribute__((ext_vector_type(4)));
typedef float f32x4 __attribute__((ext_vector_type(4)));

#define GLD_LDS16(src, dst)                                                              \
  __builtin_amdgcn_global_load_lds((const __attribute__((address_space(1))) void*)(src), \
                                   (__attribute__((address_space(3))) void*)(dst), 16, 0, 0)

#define BAR() __builtin_amdgcn_s_barrier()
#define LGKM0() asm volatile("s_waitcnt lgkmcnt(0)" ::: "memory")
#define VMCN(n) asm volatile("s_waitcnt vmcnt(" #n ")" ::: "memory")
#define SCH0() __builtin_amdgcn_sched_barrier(0)

// st_16x32 swizzle: XOR byte-bit-5 with bit-9 (within each half's 16KB region,
// layout = [8 rowgrp][2 colgrp][16 rows][32 cols] bf16; bit9 == (row&8)).
__device__ __forceinline__ int swz(int x) { return x ^ (((x >> 9) & 1) << 5); }

// ---------------------------------------------------------------------------
// fp32 -> bf16 convert, ALL tensors in one launch. blockIdx.y = segment.
// ---------------------------------------------------------------------------
struct CvtArgs {
  const float* src[7];
  bf16_t* dst[7];
  long n4[7];
};

__global__ __launch_bounds__(256) void cvt_all(CvtArgs a) {
  const int seg = blockIdx.y;
  const float* __restrict__ in = a.src[seg];
  bf16_t* __restrict__ out = a.dst[seg];
  const long n4 = a.n4[seg];
  long i = (long)blockIdx.x * blockDim.x + threadIdx.x;
  const long stride = (long)gridDim.x * blockDim.x;
  for (; i < n4; i += stride) {
    float4 v = ((const float4*)in)[i];
    bf16x4 o;
    o[0] = (bf16_t)v.x; o[1] = (bf16_t)v.y; o[2] = (bf16_t)v.z; o[3] = (bf16_t)v.w;
    ((bf16x4*)out)[i] = o;
  }
}

// ---------------------------------------------------------------------------
// Causal row softmax, in-place on bf16 scores. One 256-thread block per row.
// ---------------------------------------------------------------------------
__global__ __launch_bounds__(256) void softmax_causal(bf16_t* __restrict__ S, int n, long sB) {
  const int i = blockIdx.x;
  const int z = blockIdx.y;
  bf16_t* row = S + (long)z * sB + (long)i * n;
  const int t = threadIdx.x;
  const int j0 = t << 3;

  bf16x8 vv = ((const bf16x8*)row)[t];
  float vals[8];
  float mx = -3.0e38f;
#pragma unroll
  for (int e = 0; e < 8; ++e) {
    float v = (j0 + e <= i) ? (float)vv[e] : -3.0e38f;
    vals[e] = v;
    mx = fmaxf(mx, v);
  }
#pragma unroll
  for (int off = 32; off; off >>= 1) mx = fmaxf(mx, __shfl_xor(mx, off));
  __shared__ float redm[4];
  if ((t & 63) == 0) redm[t >> 6] = mx;
  __syncthreads();
  mx = fmaxf(fmaxf(redm[0], redm[1]), fmaxf(redm[2], redm[3]));

  float sum = 0.f;
#pragma unroll
  for (int e = 0; e < 8; ++e) {
    float p = (j0 + e <= i) ? __expf(vals[e] - mx) : 0.f;
    vals[e] = p;
    sum += p;
  }
#pragma unroll
  for (int off = 32; off; off >>= 1) sum += __shfl_xor(sum, off);
  __shared__ float reds[4];
  if ((t & 63) == 0) reds[t >> 6] = sum;
  __syncthreads();
  sum = reds[0] + reds[1] + reds[2] + reds[3];
  const float inv = 1.0f / sum;

  bf16x8 o;
#pragma unroll
  for (int e = 0; e < 8; ++e) o[e] = (bf16_t)(vals[e] * inv);
  ((bf16x8*)row)[t] = o;
}

// ---------------------------------------------------------------------------
// XCD-chunked bijective remap (requires nwg % 8 == 0; all grids comply).
// ---------------------------------------------------------------------------
__device__ __forceinline__ void xcd_remap(int& bx, int& by, int& bz) {
  const int gx = gridDim.x, gy = gridDim.y;
  int lin = (blockIdx.z * gy + blockIdx.y) * gx + blockIdx.x;
  const int nwg = gx * gy * (int)gridDim.z;
  lin = (lin & 7) * (nwg >> 3) + (lin >> 3);
  bx = lin % gx;
  const int rem = lin / gx;
  by = rem % gy;
  bz = rem / gy;
}

// ===========================================================================
// 8-phase 256x256 GEMM (BK=64, 512 thr = 8 waves as 2x4 per 128x128 quadrant).
// Pipelined: each phase = [vmcnt(N); lgkmcnt(0); 16 MFMA (frags read LAST
// phase); <=8 ds_read for NEXT phase's frags; 1 half-tile stage; barrier].
// vmcnt counts (8,8,6,-,8,8,6,-) derived from the stage/read ledger; never 0
// in steady state. One barrier/phase (all LDS regions have >=2-barrier gap
// between read-drain and restage). Tail iteration peeled (LAST).
// MODE 0: fused QKV (z = op; bias; z==2 writes transposed into vpT[b][d][n]).
// MODE 1: scores (z = batch; alpha=1/32; causal tile skip).
// ===========================================================================
struct G8Args {
  const bf16_t* A[3];
  const bf16_t* W[3];
  const float* bias[3];
  bf16_t* C[3];
  long sA, sB, sC;
};

template <int HALF, int BUF>
__device__ __forceinline__ void stage8(char* lds, const bf16_t* srcH, const int (&soff)[2],
                                       int wid, int tile) {
  const bf16_t* s = srcH + tile * 64;
  char* d = lds + (HALF >= 2 ? 65536 : 0) + BUF * 32768 + (HALF & 1) * 16384 + wid * 2048;
  GLD_LDS16(s + soff[0], d);
  GLD_LDS16(s + soff[1], d + 1024);
}

template <int BUF, int QM>
__device__ __forceinline__ void rdA(char* lds, const int (&aoffp)[4][2], bf16x8 (&af)[4][2]) {
  char* b = lds + BUF * 32768 + QM * 16384;
#pragma unroll
  for (int mi = 0; mi < 4; ++mi)
#pragma unroll
    for (int kk = 0; kk < 2; ++kk) af[mi][kk] = *(const bf16x8*)(b + aoffp[mi][kk]);
}

template <int BUF, int QN>
__device__ __forceinline__ void rdB(char* lds, const int (&boffp)[2][2], bf16x8 (&bf)[2][2]) {
  char* b = lds + 65536 + BUF * 32768 + QN * 16384;
#pragma unroll
  for (int ni = 0; ni < 2; ++ni)
#pragma unroll
    for (int kk = 0; kk < 2; ++kk) bf[ni][kk] = *(const bf16x8*)(b + boffp[ni][kk]);
}

template <int QM, int QN>
__device__ __forceinline__ void mm16(f32x4 (&acc)[2][2][4][2], const bf16x8 (&af)[4][2],
                                     const bf16x8 (&bf)[2][2]) {
  __builtin_amdgcn_s_setprio(1);
#pragma unroll
  for (int mi = 0; mi < 4; ++mi)
#pragma unroll
    for (int ni = 0; ni < 2; ++ni)
#pragma unroll
      for (int kk = 0; kk < 2; ++kk)
        acc[QM][QN][mi][ni] = __builtin_amdgcn_mfma_f32_16x16x32_bf16(
            af[mi][kk], bf[ni][kk], acc[QM][QN][mi][ni], 0, 0, 0);
  __builtin_amdgcn_s_setprio(0);
}

// One iteration = 2 K-tiles (tt even: tt -> buf0, tt+1 -> buf1), 8 phases.
template <bool LAST>
__device__ __forceinline__ void kiter(char* lds, int tt,
    const bf16_t* srcA0, const bf16_t* srcA1, const bf16_t* srcB0, const bf16_t* srcB1,
    const int (&soff)[2], int wid,
    const int (&aoffp)[4][2], const int (&boffp)[2][2],
    bf16x8 (&af)[4][2], bf16x8 (&bf0)[2][2], bf16x8 (&bf1)[2][2],
    f32x4 (&acc)[2][2][4][2]) {
  // P1: Q00(t). reads: bf1 <- t.B1 (buf0). stage (t+1).A1 -> buf1.
  VMCN(8); LGKM0(); SCH0();
  mm16<0, 0>(acc, af, bf0);
  rdB<0, 1>(lds, boffp, bf1);
  stage8<1, 1>(lds, srcA1, soff, wid, tt + 1);
  SCH0(); BAR();
  // P2: Q01(t). reads: af <- t.A1 (buf0). stage (t+2).A0 -> buf0.
  VMCN(8); LGKM0(); SCH0();
  mm16<0, 1>(acc, af, bf1);
  rdA<0, 1>(lds, aoffp, af);
  if (!LAST) stage8<0, 0>(lds, srcA0, soff, wid, tt + 2);
  SCH0(); BAR();
  // P3: Q10(t). reads: bf0 <- (t+1).B0 (buf1). stage (t+2).B0 -> buf0.
  if (LAST) { VMCN(0); } else { VMCN(6); }
  LGKM0(); SCH0();
  mm16<1, 0>(acc, af, bf0);
  rdB<1, 0>(lds, boffp, bf0);
  if (!LAST) stage8<2, 0>(lds, srcB0, soff, wid, tt + 2);
  SCH0(); BAR();
  // P4: Q11(t). reads: af <- (t+1).A0 (buf1). stage (t+2).B1 -> buf0.
  LGKM0(); SCH0();
  mm16<1, 1>(acc, af, bf1);
  rdA<1, 0>(lds, aoffp, af);
  if (!LAST) stage8<3, 0>(lds, srcB1, soff, wid, tt + 2);
  SCH0(); BAR();
  // P5: Q00(t+1). reads: bf1 <- (t+1).B1 (buf1). stage (t+2).A1 -> buf0.
  if (!LAST) { VMCN(8); }
  LGKM0(); SCH0();
  mm16<0, 0>(acc, af, bf0);
  rdB<1, 1>(lds, boffp, bf1);
  if (!LAST) stage8<1, 0>(lds, srcA1, soff, wid, tt + 2);
  SCH0(); BAR();
  // P6: Q01(t+1). reads: af <- (t+1).A1 (buf1). stage (t+3).A0 -> buf1.
  if (!LAST) { VMCN(8); }
  LGKM0(); SCH0();
  mm16<0, 1>(acc, af, bf1);
  rdA<1, 1>(lds, aoffp, af);
  if (!LAST) stage8<0, 1>(lds, srcA0, soff, wid, tt + 3);
  SCH0(); BAR();
  // P7: Q10(t+1). reads: bf0 <- (t+2).B0 (buf0). stage (t+3).B0 -> buf1.
  if (!LAST) { VMCN(6); }
  LGKM0(); SCH0();
  mm16<1, 0>(acc, af, bf0);
  if (!LAST) rdB<0, 0>(lds, boffp, bf0);
  if (!LAST) stage8<2, 1>(lds, srcB0, soff, wid, tt + 3);
  SCH0(); BAR();
  // P8: Q11(t+1). reads: af <- (t+2).A0 (buf0). stage (t+3).B1 -> buf1.
  LGKM0(); SCH0();
  mm16<1, 1>(acc, af, bf1);
  if (!LAST) rdA<0, 0>(lds, aoffp, af);
  if (!LAST) stage8<3, 1>(lds, srcB1, soff, wid, tt + 3);
  SCH0(); BAR();
}

template <int MODE>
__global__ __launch_bounds__(512, 2) void gemm8(G8Args ga) {
  int bx, by, bz;
  xcd_remap(bx, by, bz);
  const int m0 = by << 8, n0 = bx << 8;
  if (MODE == 1 && n0 > m0 + 255) return;  // uniform block exit, pre-barrier

  const int K = 1024, NT = 16;
  const bf16_t* A;
  const bf16_t* B;
  const float* bias = nullptr;
  if (MODE == 0) {
    A = ga.A[bz]; B = ga.W[bz]; bias = ga.bias[bz];
  } else {
    A = ga.A[0] + (long)bz * ga.sA;
    B = ga.W[0] + (long)bz * ga.sB;
  }

  __shared__ __align__(16) char lds[131072];

  const int t = threadIdx.x;
  const int wid = t >> 6, l = t & 63;
  const int wm = wid >> 2, wn = wid & 3;
  const int ri16 = l & 15, kg = l >> 4;

  // ---- staging source offsets: inverse of the subtiled+swizzled LDS layout.
  int soff[2];
#pragma unroll
  for (int i = 0; i < 2; ++i) {
    const int sub = wid * 2 + i;
    const int ri = l >> 2;
    const int cq = (l & 3) ^ ((ri & 8) >> 2);
    const int r = (sub >> 1) * 16 + ri;
    const int c = (sub & 1) * 32 + cq * 8;
    soff[i] = r * K + c;
  }
  const bf16_t* srcA0 = A + (long)m0 * K;
  const bf16_t* srcA1 = A + (long)(m0 + 128) * K;
  const bf16_t* srcB0 = B + (long)n0 * K;
  const bf16_t* srcB1 = B + (long)(n0 + 128) * K;

  // ---- fragment ds_read byte offsets (within a 16KB half region)
  int aoffp[4][2], boffp[2][2];
#pragma unroll
  for (int mi = 0; mi < 4; ++mi)
#pragma unroll
    for (int kk = 0; kk < 2; ++kk)
      aoffp[mi][kk] = swz((wm * 4 + mi) * 2048 + kk * 1024 + ri16 * 64 + kg * 16);
#pragma unroll
  for (int ni = 0; ni < 2; ++ni)
#pragma unroll
    for (int kk = 0; kk < 2; ++kk)
      boffp[ni][kk] = swz((wn * 2 + ni) * 2048 + kk * 1024 + ri16 * 64 + kg * 16);

  f32x4 acc[2][2][4][2] = {};
  bf16x8 af[4][2], bf0[2][2], bf1[2][2];

  // ---- prologue: stage t0 fully + t1 {A0,B0,B1}; secure t0; preload frags.
  stage8<0, 0>(lds, srcA0, soff, wid, 0);
  stage8<2, 0>(lds, srcB0, soff, wid, 0);
  stage8<3, 0>(lds, srcB1, soff, wid, 0);
  stage8<1, 0>(lds, srcA1, soff, wid, 0);
  stage8<0, 1>(lds, srcA0, soff, wid, 1);
  stage8<2, 1>(lds, srcB0, soff, wid, 1);
  stage8<3, 1>(lds, srcB1, soff, wid, 1);
  VMCN(6);  // t0's 8 loads done; t1's 6 in flight
  BAR();
  rdA<0, 0>(lds, aoffp, af);   // af  <- t0.A0
  rdB<0, 0>(lds, boffp, bf0);  // bf0 <- t0.B0

  for (int tt = 0; tt + 2 < NT; tt += 2)
    kiter<false>(lds, tt, srcA0, srcA1, srcB0, srcB1, soff, wid, aoffp, boffp,
                 af, bf0, bf1, acc);
  kiter<true>(lds, NT - 2, srcA0, srcA1, srcB0, srcB1, soff, wid, aoffp, boffp,
              af, bf0, bf1, acc);

  // ---- epilogue: C row = m0+qm*128+wm*64+mi*16+kg*4+j; col = n0+qn*128+wn*32+ni*16+ri16
  if (MODE == 0) {
    if (bz < 2) {
      bf16_t* C = ga.C[bz];  // [8192,1024]
#pragma unroll
      for (int qm = 0; qm < 2; ++qm)
#pragma unroll
        for (int qn = 0; qn < 2; ++qn)
#pragma unroll
          for (int mi = 0; mi < 4; ++mi)
#pragma unroll
            for (int ni = 0; ni < 2; ++ni) {
              const int col = n0 + qn * 128 + wn * 32 + ni * 16 + ri16;
              const int row0 = m0 + qm * 128 + wm * 64 + mi * 16 + kg * 4;
              const float badd = bias[col];
#pragma unroll
              for (int j = 0; j < 4; ++j)
                C[(long)(row0 + j) * 1024 + col] = (bf16_t)(acc[qm][qn][mi][ni][j] + badd);
            }
    } else {
      bf16_t* C = ga.C[2];  // vpT: per-batch [1024][2048]
#pragma unroll
      for (int qm = 0; qm < 2; ++qm)
#pragma unroll
        for (int qn = 0; qn < 2; ++qn)
#pragma unroll
          for (int mi = 0; mi < 4; ++mi)
#pragma unroll
            for (int ni = 0; ni < 2; ++ni) {
              const int col = n0 + qn * 128 + wn * 32 + ni * 16 + ri16;
              const int row0 = m0 + qm * 128 + wm * 64 + mi * 16 + kg * 4;
              const float badd = bias[col];
              const int batch = row0 >> 11, nr = row0 & 2047;
              bf16x4 o;
#pragma unroll
              for (int j = 0; j < 4; ++j) o[j] = (bf16_t)(acc[qm][qn][mi][ni][j] + badd);
              *(bf16x4*)(C + (long)batch * (2048 * 1024) + (long)col * 2048 + nr) = o;
            }
    }
  } else {
    bf16_t* C = ga.C[0] + (long)bz * ga.sC;  // S[z]: [2048,2048]
#pragma unroll
    for (int qm = 0; qm < 2; ++qm)
#pragma unroll
      for (int qn = 0; qn < 2; ++qn)
#pragma unroll
        for (int mi = 0; mi < 4; ++mi)
#pragma unroll
          for (int ni = 0; ni < 2; ++ni) {
            const int col = n0 + qn * 128 + wn * 32 + ni * 16 + ri16;
            const int row0 = m0 + qm * 128 + wm * 64 + mi * 16 + kg * 4;
#pragma unroll
            for (int j = 0; j < 4; ++j)
              C[(long)(row0 + j) * 2048 + col] = (bf16_t)(acc[qm][qn][mi][ni][j] * 0.03125f);
          }
  }
}

// ---------------------------------------------------------------------------
// 128x128 m97-structure GEMM (kept for PV + out-proj; proven in R1-R3).
// ---------------------------------------------------------------------------
template <bool BF16_OUT, bool BIAS, bool KBOUND>
__device__ __forceinline__ void gemm_body(const bf16_t* __restrict__ A,
                                          const bf16_t* __restrict__ B,
                                          const float* __restrict__ bias,
                                          void* __restrict__ Cout,
                                          int N, int K, float alpha,
                                          int m0, int n0) {
  int KT = K >> 5;
  if (KBOUND) {
    int kb = (n0 + 128) >> 5;
    if (kb < KT) KT = kb;
  }

  __shared__ __align__(16) bf16_t As[128 * 32];
  __shared__ __align__(16) bf16_t Bs[128 * 32];

  const int t = threadIdx.x;
  const int l = t & 63;
  const int w = t >> 6;
  const int wr = w >> 1, wc = w & 1;

  const int c0 = t, c1 = t + 256;
  const bf16_t* a_src0 = A + (long)(m0 + (c0 >> 2)) * K + ((c0 & 3) << 3);
  const bf16_t* a_src1 = A + (long)(m0 + (c1 >> 2)) * K + ((c1 & 3) << 3);
  const bf16_t* b_src0 = B + (long)(n0 + (c0 >> 2)) * K + ((c0 & 3) << 3);
  const bf16_t* b_src1 = B + (long)(n0 + (c1 >> 2)) * K + ((c1 & 3) << 3);
  char* const asb = (char*)As;
  char* const bsb = (char*)Bs;
  char* const a_dst0 = asb + w * 1024;
  char* const a_dst1 = asb + 4096 + w * 1024;
  char* const b_dst0 = bsb + w * 1024;
  char* const b_dst1 = bsb + 4096 + w * 1024;

  const int r16 = l & 15, kg = l >> 4;
  int aoff[4], boff[4];
#pragma unroll
  for (int mi = 0; mi < 4; ++mi) aoff[mi] = (((wr * 64 + mi * 16 + r16) * 32) + kg * 8) * 2;
#pragma unroll
  for (int ni = 0; ni < 4; ++ni) boff[ni] = (((wc * 64 + ni * 16 + r16) * 32) + kg * 8) * 2;

  f32x4 acc[4][4] = {};

  for (int kt = 0; kt < KT; ++kt) {
    __syncthreads();
    GLD_LDS16(a_src0, a_dst0);
    GLD_LDS16(a_src1, a_dst1);
    GLD_LDS16(b_src0, b_dst0);
    GLD_LDS16(b_src1, b_dst1);
    a_src0 += 32; a_src1 += 32; b_src0 += 32; b_src1 += 32;
    __syncthreads();

    bf16x8 af[4], bfr[4];
#pragma unroll
    for (int mi = 0; mi < 4; ++mi) af[mi] = *(const bf16x8*)(asb + aoff[mi]);
#pragma unroll
    for (int ni = 0; ni < 4; ++ni) bfr[ni] = *(const bf16x8*)(bsb + boff[ni]);
#pragma unroll
    for (int mi = 0; mi < 4; ++mi)
#pragma unroll
      for (int ni = 0; ni < 4; ++ni)
        acc[mi][ni] = __builtin_amdgcn_mfma_f32_16x16x32_bf16(af[mi], bfr[ni], acc[mi][ni], 0, 0, 0);
  }

  const int rowbase = m0 + wr * 64 + ((l >> 4) << 2);
  const int colbase = n0 + wc * 64 + (l & 15);
  if constexpr (BF16_OUT) {
    bf16_t* C = (bf16_t*)Cout;
#pragma unroll
    for (int mi = 0; mi < 4; ++mi)
#pragma unroll
      for (int ni = 0; ni < 4; ++ni) {
        const int col = colbase + ni * 16;
        float badd = 0.f;
        if constexpr (BIAS) badd = bias[col];
#pragma unroll
        for (int j = 0; j < 4; ++j) {
          float v = acc[mi][ni][j] * alpha + badd;
          C[(long)(rowbase + mi * 16 + j) * N + col] = (bf16_t)v;
        }
      }
  } else {
    float* C = (float*)Cout;
#pragma unroll
    for (int mi = 0; mi < 4; ++mi)
#pragma unroll
      for (int ni = 0; ni < 4; ++ni) {
        const int col = colbase + ni * 16;
        float badd = 0.f;
        if constexpr (BIAS) badd = bias[col];
#pragma unroll
        for (int j = 0; j < 4; ++j) {
          float v = acc[mi][ni][j] * alpha + badd;
          C[(long)(rowbase + mi * 16 + j) * N + col] = v;
        }
      }
  }
}

template <bool BF16_OUT, bool BIAS, bool KBOUND>
__global__ __launch_bounds__(256, 4) void gemm_bt(const bf16_t* __restrict__ A,
                                                  const bf16_t* __restrict__ B,
                                                  const float* __restrict__ bias,
                                                  void* __restrict__ Cout,
                                                  int N, int K, float alpha,
                                                  long sAb, long sBb, long sCb, int eltC) {
  int bx, by, bz;
  xcd_remap(bx, by, bz);
  const int m0 = by << 7, n0 = bx << 7;
  gemm_body<BF16_OUT, BIAS, KBOUND>(A + (long)bz * sAb, B + (long)bz * sBb, bias,
                                    (char*)Cout + (long)bz * sCb * eltC, N, K, alpha, m0, n0);
}

// ---------------------------------------------------------------------------
extern "C" void kernel_launch(void* const* d_in, const int* in_sizes, int n_in,
                              void* d_out, int out_size, void* d_ws, size_t ws_size,
                              hipStream_t stream) {
  const int b = 4, n = 2048, d = 1024;
  const long nd  = (long)n * d;
  const long bn  = (long)b * n;
  const long bnd = bn * d;
  const long ddl = (long)d * d;
  const long nn  = (long)n * n;

  const float* q  = (const float*)d_in[0];
  const float* k  = (const float*)d_in[1];
  const float* v  = (const float*)d_in[2];
  const float* Wq = (const float*)d_in[3];
  const float* bq = (const float*)d_in[4];
  const float* Wk = (const float*)d_in[5];
  const float* bk = (const float*)d_in[6];
  const float* Wv = (const float*)d_in[7];
  const float* bv = (const float*)d_in[8];
  const float* Wo = (const float*)d_in[9];
  const float* bo = (const float*)d_in[10];

  bf16_t* ws  = (bf16_t*)d_ws;
  bf16_t* qB  = ws;
  bf16_t* kB  = qB + bnd;
  bf16_t* vB  = kB + bnd;
  bf16_t* WqB = vB + bnd;
  bf16_t* WkB = WqB + ddl;
  bf16_t* WvB = WkB + ddl;
  bf16_t* WoB = WvB + ddl;
  bf16_t* qpB = WoB + ddl;
  bf16_t* kpB = qpB + bnd;
  bf16_t* vpT = kpB + bnd;       // per-batch [d][n] (written by V-proj epilogue)
  bf16_t* S   = vpT + bnd;
  bf16_t* yT  = S + (long)b * nn;
  const size_t need = (size_t)(7 * bnd + 4 * ddl + (long)b * nn) * 2;
  if (ws_size < need) return;

  dim3 blk(256);

  // fp32 -> bf16 converts: ONE launch, 7 segments
  CvtArgs ca;
  ca.src[0] = q;  ca.dst[0] = qB;  ca.n4[0] = bnd / 4;
  ca.src[1] = k;  ca.dst[1] = kB;  ca.n4[1] = bnd / 4;
  ca.src[2] = v;  ca.dst[2] = vB;  ca.n4[2] = bnd / 4;
  ca.src[3] = Wq; ca.dst[3] = WqB; ca.n4[3] = ddl / 4;
  ca.src[4] = Wk; ca.dst[4] = WkB; ca.n4[4] = ddl / 4;
  ca.src[5] = Wv; ca.dst[5] = WvB; ca.n4[5] = ddl / 4;
  ca.src[6] = Wo; ca.dst[6] = WoB; ca.n4[6] = ddl / 4;
  cvt_all<<<dim3(512, 7), blk, 0, stream>>>(ca);

  // fused QKV projections, 8-phase 256^2 kernel: grid (4, 32, 3) = 384 blocks
  G8Args qa = {};
  qa.A[0] = qB; qa.W[0] = WqB; qa.bias[0] = bq; qa.C[0] = qpB;
  qa.A[1] = kB; qa.W[1] = WkB; qa.bias[1] = bk; qa.C[1] = kpB;
  qa.A[2] = vB; qa.W[2] = WvB; qa.bias[2] = bv; qa.C[2] = vpT;  // V writes transposed
  gemm8<0><<<dim3(d / 256, bn / 256, 3), dim3(512), 0, stream>>>(qa);

  // scores: S[z] = qp[z] x kp[z]^T * (1/32), 8-phase, causal tile-skip
  G8Args sa = {};
  sa.A[0] = qpB; sa.W[0] = kpB; sa.C[0] = S;
  sa.sA = nd; sa.sB = nd; sa.sC = nn;
  gemm8<1><<<dim3(n / 256, n / 256, b), dim3(512), 0, stream>>>(sa);

  // causal softmax in place
  softmax_causal<<<dim3(n, b), blk, 0, stream>>>(S, n, nn);

  // yT[z] = vpT[z] x P[z]^T   (128^2 kernel, K bounded per N-tile by causality)
  gemm_bt<true, false, true><<<dim3(n / 128, d / 128, b), blk, 0, stream>>>(
      vpT, S, nullptr, yT, n, n, 1.f, nd, nn, nd, 2);

  // out = y2 x Wo^T + bo ; y2 flat == yT flat, fp32 out
  gemm_bt<false, true, false><<<dim3(d / 128, bn / 128, 1), blk, 0, stream>>>(
      yT, WoB, bo, (float*)d_out, d, d, 1.f, 0, 0, 0, 4);
}

// Round 6
// 203.571 us; speedup vs baseline: 1.3821x; 1.0350x over previous
//
#include <hip/hip_runtime.h>
#include <hip/hip_bf16.h>
#include <stdint.h>

typedef __bf16 bf16_t;
typedef __bf16 bf16x8 __attribute__((ext_vector_type(8)));
typedef __bf16 bf16x4 __attribute__((ext_vector_type(4)));
typedef float f32x4 __attribute__((ext_vector_type(4)));

#define GLD_LDS16(src, dst)                                                              \
  __builtin_amdgcn_global_load_lds((const __attribute__((address_space(1))) void*)(src), \
                                   (__attribute__((address_space(3))) void*)(dst), 16, 0, 0)

#define BAR() __builtin_amdgcn_s_barrier()
#define LGKM0() asm volatile("s_waitcnt lgkmcnt(0)" ::: "memory")
#define VMCN(n) asm volatile("s_waitcnt vmcnt(" #n ")" ::: "memory")
#define SCH0() __builtin_amdgcn_sched_barrier(0)

__device__ __forceinline__ int swz(int x) { return x ^ (((x >> 9) & 1) << 5); }

// ---------------------------------------------------------------------------
// fp32 -> bf16 convert (weights only now). blockIdx.y = segment.
// ---------------------------------------------------------------------------
struct CvtArgs {
  const float* src[4];
  bf16_t* dst[4];
  long n4[4];
};

__global__ __launch_bounds__(256) void cvt_all(CvtArgs a) {
  const int seg = blockIdx.y;
  const float* __restrict__ in = a.src[seg];
  bf16_t* __restrict__ out = a.dst[seg];
  const long n4 = a.n4[seg];
  long i = (long)blockIdx.x * blockDim.x + threadIdx.x;
  const long stride = (long)gridDim.x * blockDim.x;
  for (; i < n4; i += stride) {
    float4 v = ((const float4*)in)[i];
    bf16x4 o;
    o[0] = (bf16_t)v.x; o[1] = (bf16_t)v.y; o[2] = (bf16_t)v.z; o[3] = (bf16_t)v.w;
    ((bf16x4*)out)[i] = o;
  }
}

// ---------------------------------------------------------------------------
// Causal row softmax, in-place, bounded: row i only touches
// j < jmax = (floor(i/128)+1)*128 (PV's KBOUND never reads past jmax; the
// region beyond stays untouched garbage by design).
// ---------------------------------------------------------------------------
__global__ __launch_bounds__(256) void softmax_causal(bf16_t* __restrict__ S, int n, long sB) {
  const int i = blockIdx.x;
  const int z = blockIdx.y;
  bf16_t* row = S + (long)z * sB + (long)i * n;
  const int t = threadIdx.x;
  const int j0 = t << 3;
  const int jmax = ((i >> 7) + 1) << 7;
  const bool active = j0 < jmax;

  float vals[8];
  float mx = -3.0e38f;
  if (active) {
    bf16x8 vv = ((const bf16x8*)row)[t];
#pragma unroll
    for (int e = 0; e < 8; ++e) {
      float v = (j0 + e <= i) ? (float)vv[e] : -3.0e38f;
      vals[e] = v;
      mx = fmaxf(mx, v);
    }
  }
#pragma unroll
  for (int off = 32; off; off >>= 1) mx = fmaxf(mx, __shfl_xor(mx, off));
  __shared__ float redm[4];
  if ((t & 63) == 0) redm[t >> 6] = mx;
  __syncthreads();
  mx = fmaxf(fmaxf(redm[0], redm[1]), fmaxf(redm[2], redm[3]));

  float sum = 0.f;
  if (active) {
#pragma unroll
    for (int e = 0; e < 8; ++e) {
      float p = (j0 + e <= i) ? __expf(vals[e] - mx) : 0.f;
      vals[e] = p;
      sum += p;
    }
  }
#pragma unroll
  for (int off = 32; off; off >>= 1) sum += __shfl_xor(sum, off);
  __shared__ float reds[4];
  if ((t & 63) == 0) reds[t >> 6] = sum;
  __syncthreads();
  sum = reds[0] + reds[1] + reds[2] + reds[3];
  const float inv = 1.0f / sum;

  if (active) {
    bf16x8 o;
#pragma unroll
    for (int e = 0; e < 8; ++e) o[e] = (bf16_t)(vals[e] * inv);
    ((bf16x8*)row)[t] = o;
  }
}

// ---------------------------------------------------------------------------
// XCD-chunked bijective remap (requires nwg % 8 == 0; all grids comply).
// ---------------------------------------------------------------------------
__device__ __forceinline__ void xcd_remap(int& bx, int& by, int& bz) {
  const int gx = gridDim.x, gy = gridDim.y;
  int lin = (blockIdx.z * gy + blockIdx.y) * gx + blockIdx.x;
  const int nwg = gx * gy * (int)gridDim.z;
  lin = (lin & 7) * (nwg >> 3) + (lin >> 3);
  bx = lin % gx;
  const int rem = lin / gx;
  by = rem % gy;
  bz = rem / gy;
}

// ===========================================================================
// 8-phase 256x256 GEMM — unchanged from R5 (used for scores only).
// ===========================================================================
struct G8Args {
  const bf16_t* A[3];
  const bf16_t* W[3];
  const float* bias[3];
  bf16_t* C[3];
  long sA, sB, sC;
};

template <int HALF, int BUF>
__device__ __forceinline__ void stage8(char* lds, const bf16_t* srcH, const int (&soff)[2],
                                       int wid, int tile) {
  const bf16_t* s = srcH + tile * 64;
  char* d = lds + (HALF >= 2 ? 65536 : 0) + BUF * 32768 + (HALF & 1) * 16384 + wid * 2048;
  GLD_LDS16(s + soff[0], d);
  GLD_LDS16(s + soff[1], d + 1024);
}

template <int BUF, int QM>
__device__ __forceinline__ void rdA(char* lds, const int (&aoffp)[4][2], bf16x8 (&af)[4][2]) {
  char* b = lds + BUF * 32768 + QM * 16384;
#pragma unroll
  for (int mi = 0; mi < 4; ++mi)
#pragma unroll
    for (int kk = 0; kk < 2; ++kk) af[mi][kk] = *(const bf16x8*)(b + aoffp[mi][kk]);
}

template <int BUF, int QN>
__device__ __forceinline__ void rdB(char* lds, const int (&boffp)[2][2], bf16x8 (&bf)[2][2]) {
  char* b = lds + 65536 + BUF * 32768 + QN * 16384;
#pragma unroll
  for (int ni = 0; ni < 2; ++ni)
#pragma unroll
    for (int kk = 0; kk < 2; ++kk) bf[ni][kk] = *(const bf16x8*)(b + boffp[ni][kk]);
}

template <int QM, int QN>
__device__ __forceinline__ void mm16(f32x4 (&acc)[2][2][4][2], const bf16x8 (&af)[4][2],
                                     const bf16x8 (&bf)[2][2]) {
  __builtin_amdgcn_s_setprio(1);
#pragma unroll
  for (int mi = 0; mi < 4; ++mi)
#pragma unroll
    for (int ni = 0; ni < 2; ++ni)
#pragma unroll
      for (int kk = 0; kk < 2; ++kk)
        acc[QM][QN][mi][ni] = __builtin_amdgcn_mfma_f32_16x16x32_bf16(
            af[mi][kk], bf[ni][kk], acc[QM][QN][mi][ni], 0, 0, 0);
  __builtin_amdgcn_s_setprio(0);
}

template <bool LAST>
__device__ __forceinline__ void kiter(char* lds, int tt,
    const bf16_t* srcA0, const bf16_t* srcA1, const bf16_t* srcB0, const bf16_t* srcB1,
    const int (&soff)[2], int wid,
    const int (&aoffp)[4][2], const int (&boffp)[2][2],
    bf16x8 (&af)[4][2], bf16x8 (&bf0)[2][2], bf16x8 (&bf1)[2][2],
    f32x4 (&acc)[2][2][4][2]) {
  VMCN(8); LGKM0(); SCH0();
  mm16<0, 0>(acc, af, bf0);
  rdB<0, 1>(lds, boffp, bf1);
  stage8<1, 1>(lds, srcA1, soff, wid, tt + 1);
  SCH0(); BAR();
  VMCN(8); LGKM0(); SCH0();
  mm16<0, 1>(acc, af, bf1);
  rdA<0, 1>(lds, aoffp, af);
  if (!LAST) stage8<0, 0>(lds, srcA0, soff, wid, tt + 2);
  SCH0(); BAR();
  if (LAST) { VMCN(0); } else { VMCN(6); }
  LGKM0(); SCH0();
  mm16<1, 0>(acc, af, bf0);
  rdB<1, 0>(lds, boffp, bf0);
  if (!LAST) stage8<2, 0>(lds, srcB0, soff, wid, tt + 2);
  SCH0(); BAR();
  LGKM0(); SCH0();
  mm16<1, 1>(acc, af, bf1);
  rdA<1, 0>(lds, aoffp, af);
  if (!LAST) stage8<3, 0>(lds, srcB1, soff, wid, tt + 2);
  SCH0(); BAR();
  if (!LAST) { VMCN(8); }
  LGKM0(); SCH0();
  mm16<0, 0>(acc, af, bf0);
  rdB<1, 1>(lds, boffp, bf1);
  if (!LAST) stage8<1, 0>(lds, srcA1, soff, wid, tt + 2);
  SCH0(); BAR();
  if (!LAST) { VMCN(8); }
  LGKM0(); SCH0();
  mm16<0, 1>(acc, af, bf1);
  rdA<1, 1>(lds, aoffp, af);
  if (!LAST) stage8<0, 1>(lds, srcA0, soff, wid, tt + 3);
  SCH0(); BAR();
  if (!LAST) { VMCN(6); }
  LGKM0(); SCH0();
  mm16<1, 0>(acc, af, bf0);
  if (!LAST) rdB<0, 0>(lds, boffp, bf0);
  if (!LAST) stage8<2, 1>(lds, srcB0, soff, wid, tt + 3);
  SCH0(); BAR();
  LGKM0(); SCH0();
  mm16<1, 1>(acc, af, bf1);
  if (!LAST) rdA<0, 0>(lds, aoffp, af);
  if (!LAST) stage8<3, 1>(lds, srcB1, soff, wid, tt + 3);
  SCH0(); BAR();
}

// MODE 1 only now: scores (z = batch; alpha=1/32; causal tile skip).
template <int MODE>
__global__ __launch_bounds__(512, 2) void gemm8(G8Args ga) {
  int bx, by, bz;
  xcd_remap(bx, by, bz);
  const int m0 = by << 8, n0 = bx << 8;
  if (MODE == 1 && n0 > m0 + 255) return;

  const int K = 1024, NT = 16;
  const bf16_t* A = ga.A[0] + (long)bz * ga.sA;
  const bf16_t* B = ga.W[0] + (long)bz * ga.sB;

  __shared__ __align__(16) char lds[131072];

  const int t = threadIdx.x;
  const int wid = t >> 6, l = t & 63;
  const int wm = wid >> 2, wn = wid & 3;
  const int ri16 = l & 15, kg = l >> 4;

  int soff[2];
#pragma unroll
  for (int i = 0; i < 2; ++i) {
    const int sub = wid * 2 + i;
    const int ri = l >> 2;
    const int cq = (l & 3) ^ ((ri & 8) >> 2);
    const int r = (sub >> 1) * 16 + ri;
    const int c = (sub & 1) * 32 + cq * 8;
    soff[i] = r * K + c;
  }
  const bf16_t* srcA0 = A + (long)m0 * K;
  const bf16_t* srcA1 = A + (long)(m0 + 128) * K;
  const bf16_t* srcB0 = B + (long)n0 * K;
  const bf16_t* srcB1 = B + (long)(n0 + 128) * K;

  int aoffp[4][2], boffp[2][2];
#pragma unroll
  for (int mi = 0; mi < 4; ++mi)
#pragma unroll
    for (int kk = 0; kk < 2; ++kk)
      aoffp[mi][kk] = swz((wm * 4 + mi) * 2048 + kk * 1024 + ri16 * 64 + kg * 16);
#pragma unroll
  for (int ni = 0; ni < 2; ++ni)
#pragma unroll
    for (int kk = 0; kk < 2; ++kk)
      boffp[ni][kk] = swz((wn * 2 + ni) * 2048 + kk * 1024 + ri16 * 64 + kg * 16);

  f32x4 acc[2][2][4][2] = {};
  bf16x8 af[4][2], bf0[2][2], bf1[2][2];

  stage8<0, 0>(lds, srcA0, soff, wid, 0);
  stage8<2, 0>(lds, srcB0, soff, wid, 0);
  stage8<3, 0>(lds, srcB1, soff, wid, 0);
  stage8<1, 0>(lds, srcA1, soff, wid, 0);
  stage8<0, 1>(lds, srcA0, soff, wid, 1);
  stage8<2, 1>(lds, srcB0, soff, wid, 1);
  stage8<3, 1>(lds, srcB1, soff, wid, 1);
  VMCN(6);
  BAR();
  rdA<0, 0>(lds, aoffp, af);
  rdB<0, 0>(lds, boffp, bf0);

  for (int tt = 0; tt + 2 < NT; tt += 2)
    kiter<false>(lds, tt, srcA0, srcA1, srcB0, srcB1, soff, wid, aoffp, boffp,
                 af, bf0, bf1, acc);
  kiter<true>(lds, NT - 2, srcA0, srcA1, srcB0, srcB1, soff, wid, aoffp, boffp,
              af, bf0, bf1, acc);

  bf16_t* C = ga.C[0] + (long)bz * ga.sC;  // S[z]: [2048,2048]
#pragma unroll
  for (int qm = 0; qm < 2; ++qm)
#pragma unroll
    for (int qn = 0; qn < 2; ++qn)
#pragma unroll
      for (int mi = 0; mi < 4; ++mi)
#pragma unroll
        for (int ni = 0; ni < 2; ++ni) {
          const int col = n0 + qn * 128 + wn * 32 + ni * 16 + ri16;
          const int row0 = m0 + qm * 128 + wm * 64 + mi * 16 + kg * 4;
#pragma unroll
          for (int j = 0; j < 4; ++j)
            C[(long)(row0 + j) * 2048 + col] = (bf16_t)(acc[qm][qn][mi][ni][j] * 0.03125f);
        }
}

// ---------------------------------------------------------------------------
// 128x128 m97-structure GEMM (PV + out-proj).
// ---------------------------------------------------------------------------
template <bool BF16_OUT, bool BIAS, bool KBOUND>
__device__ __forceinline__ void gemm_body(const bf16_t* __restrict__ A,
                                          const bf16_t* __restrict__ B,
                                          const float* __restrict__ bias,
                                          void* __restrict__ Cout,
                                          int N, int K, float alpha,
                                          int m0, int n0) {
  int KT = K >> 5;
  if (KBOUND) {
    int kb = (n0 + 128) >> 5;
    if (kb < KT) KT = kb;
  }

  __shared__ __align__(16) bf16_t As[128 * 32];
  __shared__ __align__(16) bf16_t Bs[128 * 32];

  const int t = threadIdx.x;
  const int l = t & 63;
  const int w = t >> 6;
  const int wr = w >> 1, wc = w & 1;

  const int c0 = t, c1 = t + 256;
  const bf16_t* a_src0 = A + (long)(m0 + (c0 >> 2)) * K + ((c0 & 3) << 3);
  const bf16_t* a_src1 = A + (long)(m0 + (c1 >> 2)) * K + ((c1 & 3) << 3);
  const bf16_t* b_src0 = B + (long)(n0 + (c0 >> 2)) * K + ((c0 & 3) << 3);
  const bf16_t* b_src1 = B + (long)(n0 + (c1 >> 2)) * K + ((c1 & 3) << 3);
  char* const asb = (char*)As;
  char* const bsb = (char*)Bs;
  char* const a_dst0 = asb + w * 1024;
  char* const a_dst1 = asb + 4096 + w * 1024;
  char* const b_dst0 = bsb + w * 1024;
  char* const b_dst1 = bsb + 4096 + w * 1024;

  const int r16 = l & 15, kg = l >> 4;
  int aoff[4], boff[4];
#pragma unroll
  for (int mi = 0; mi < 4; ++mi) aoff[mi] = (((wr * 64 + mi * 16 + r16) * 32) + kg * 8) * 2;
#pragma unroll
  for (int ni = 0; ni < 4; ++ni) boff[ni] = (((wc * 64 + ni * 16 + r16) * 32) + kg * 8) * 2;

  f32x4 acc[4][4] = {};

  for (int kt = 0; kt < KT; ++kt) {
    __syncthreads();
    GLD_LDS16(a_src0, a_dst0);
    GLD_LDS16(a_src1, a_dst1);
    GLD_LDS16(b_src0, b_dst0);
    GLD_LDS16(b_src1, b_dst1);
    a_src0 += 32; a_src1 += 32; b_src0 += 32; b_src1 += 32;
    __syncthreads();

    bf16x8 af[4], bfr[4];
#pragma unroll
    for (int mi = 0; mi < 4; ++mi) af[mi] = *(const bf16x8*)(asb + aoff[mi]);
#pragma unroll
    for (int ni = 0; ni < 4; ++ni) bfr[ni] = *(const bf16x8*)(bsb + boff[ni]);
#pragma unroll
    for (int mi = 0; mi < 4; ++mi)
#pragma unroll
      for (int ni = 0; ni < 4; ++ni)
        acc[mi][ni] = __builtin_amdgcn_mfma_f32_16x16x32_bf16(af[mi], bfr[ni], acc[mi][ni], 0, 0, 0);
  }

  const int rowbase = m0 + wr * 64 + ((l >> 4) << 2);
  const int colbase = n0 + wc * 64 + (l & 15);
  if constexpr (BF16_OUT) {
    bf16_t* C = (bf16_t*)Cout;
#pragma unroll
    for (int mi = 0; mi < 4; ++mi)
#pragma unroll
      for (int ni = 0; ni < 4; ++ni) {
        const int col = colbase + ni * 16;
        float badd = 0.f;
        if constexpr (BIAS) badd = bias[col];
#pragma unroll
        for (int j = 0; j < 4; ++j) {
          float v = acc[mi][ni][j] * alpha + badd;
          C[(long)(rowbase + mi * 16 + j) * N + col] = (bf16_t)v;
        }
      }
  } else {
    float* C = (float*)Cout;
#pragma unroll
    for (int mi = 0; mi < 4; ++mi)
#pragma unroll
      for (int ni = 0; ni < 4; ++ni) {
        const int col = colbase + ni * 16;
        float badd = 0.f;
        if constexpr (BIAS) badd = bias[col];
#pragma unroll
        for (int j = 0; j < 4; ++j) {
          float v = acc[mi][ni][j] * alpha + badd;
          C[(long)(rowbase + mi * 16 + j) * N + col] = v;
        }
      }
  }
}

template <bool BF16_OUT, bool BIAS, bool KBOUND>
__global__ __launch_bounds__(256, 4) void gemm_bt(const bf16_t* __restrict__ A,
                                                  const bf16_t* __restrict__ B,
                                                  const float* __restrict__ bias,
                                                  void* __restrict__ Cout,
                                                  int N, int K, float alpha,
                                                  long sAb, long sBb, long sCb, int eltC) {
  int bx, by, bz;
  xcd_remap(bx, by, bz);
  const int m0 = by << 7, n0 = bx << 7;
  gemm_body<BF16_OUT, BIAS, KBOUND>(A + (long)bz * sAb, B + (long)bz * sBb, bias,
                                    (char*)Cout + (long)bz * sCb * eltC, N, K, alpha, m0, n0);
}

// ---------------------------------------------------------------------------
// QKV projection, m97 128x128 structure, A read DIRECTLY as fp32 (reg-staged:
// 2x float4 -> cvt -> ds_write_b128, layout identical to the gload_lds
// placement). B = bf16 weights via global_load_lds. z selects op; z==2 (V)
// writes its output transposed into vpT[b][d][n].
// ---------------------------------------------------------------------------
struct QkvArgsF {
  const float* A[3];
  const bf16_t* W[3];
  const float* bias[3];
  bf16_t* C[3];
};

__global__ __launch_bounds__(256, 4) void gemm_qkv_f32a(QkvArgsF ga, int N, int K) {
  int bx, by, bz;
  xcd_remap(bx, by, bz);
  const int m0 = by << 7, n0 = bx << 7;

  const float* __restrict__ A = ga.A[bz];
  const bf16_t* __restrict__ B = ga.W[bz];
  const float* __restrict__ bias = ga.bias[bz];

  const int KT = K >> 5;

  __shared__ __align__(16) bf16_t As[128 * 32];
  __shared__ __align__(16) bf16_t Bs[128 * 32];

  const int t = threadIdx.x;
  const int l = t & 63;
  const int w = t >> 6;
  const int wr = w >> 1, wc = w & 1;

  const int c0 = t, c1 = t + 256;
  const float* a_src0 = A + (long)(m0 + (c0 >> 2)) * K + ((c0 & 3) << 3);
  const float* a_src1 = A + (long)(m0 + (c1 >> 2)) * K + ((c1 & 3) << 3);
  const bf16_t* b_src0 = B + (long)(n0 + (c0 >> 2)) * K + ((c0 & 3) << 3);
  const bf16_t* b_src1 = B + (long)(n0 + (c1 >> 2)) * K + ((c1 & 3) << 3);
  char* const asb = (char*)As;
  char* const bsb = (char*)Bs;
  char* const b_dst0 = bsb + w * 1024;
  char* const b_dst1 = bsb + 4096 + w * 1024;

  const int r16 = l & 15, kg = l >> 4;
  int aoff[4], boff[4];
#pragma unroll
  for (int mi = 0; mi < 4; ++mi) aoff[mi] = (((wr * 64 + mi * 16 + r16) * 32) + kg * 8) * 2;
#pragma unroll
  for (int ni = 0; ni < 4; ++ni) boff[ni] = (((wc * 64 + ni * 16 + r16) * 32) + kg * 8) * 2;

  f32x4 acc[4][4] = {};

  for (int kt = 0; kt < KT; ++kt) {
    __syncthreads();
    // A: fp32 -> regs -> cvt -> LDS (chunk c lives at byte c*16, same as DMA).
    float4 x0 = *(const float4*)(a_src0);
    float4 x1 = *(const float4*)(a_src0 + 4);
    float4 y0 = *(const float4*)(a_src1);
    float4 y1 = *(const float4*)(a_src1 + 4);
    // B: direct DMA.
    GLD_LDS16(b_src0, b_dst0);
    GLD_LDS16(b_src1, b_dst1);
    bf16x8 wa, wb;
    wa[0] = (bf16_t)x0.x; wa[1] = (bf16_t)x0.y; wa[2] = (bf16_t)x0.z; wa[3] = (bf16_t)x0.w;
    wa[4] = (bf16_t)x1.x; wa[5] = (bf16_t)x1.y; wa[6] = (bf16_t)x1.z; wa[7] = (bf16_t)x1.w;
    wb[0] = (bf16_t)y0.x; wb[1] = (bf16_t)y0.y; wb[2] = (bf16_t)y0.z; wb[3] = (bf16_t)y0.w;
    wb[4] = (bf16_t)y1.x; wb[5] = (bf16_t)y1.y; wb[6] = (bf16_t)y1.z; wb[7] = (bf16_t)y1.w;
    *(bf16x8*)(asb + c0 * 16) = wa;
    *(bf16x8*)(asb + c1 * 16) = wb;
    a_src0 += 32; a_src1 += 32; b_src0 += 32; b_src1 += 32;
    __syncthreads();

    bf16x8 af[4], bfr[4];
#pragma unroll
    for (int mi = 0; mi < 4; ++mi) af[mi] = *(const bf16x8*)(asb + aoff[mi]);
#pragma unroll
    for (int ni = 0; ni < 4; ++ni) bfr[ni] = *(const bf16x8*)(bsb + boff[ni]);
#pragma unroll
    for (int mi = 0; mi < 4; ++mi)
#pragma unroll
      for (int ni = 0; ni < 4; ++ni)
        acc[mi][ni] = __builtin_amdgcn_mfma_f32_16x16x32_bf16(af[mi], bfr[ni], acc[mi][ni], 0, 0, 0);
  }

  const int rowbase = m0 + wr * 64 + ((l >> 4) << 2);
  const int colbase = n0 + wc * 64 + (l & 15);
  if (bz < 2) {
    bf16_t* C = ga.C[bz];  // [8192,1024]
#pragma unroll
    for (int mi = 0; mi < 4; ++mi)
#pragma unroll
      for (int ni = 0; ni < 4; ++ni) {
        const int col = colbase + ni * 16;
        const float badd = bias[col];
#pragma unroll
        for (int j = 0; j < 4; ++j)
          C[(long)(rowbase + mi * 16 + j) * N + col] = (bf16_t)(acc[mi][ni][j] + badd);
      }
  } else {
    bf16_t* C = ga.C[2];  // vpT: per-batch [1024][2048]
#pragma unroll
    for (int mi = 0; mi < 4; ++mi)
#pragma unroll
      for (int ni = 0; ni < 4; ++ni) {
        const int col = colbase + ni * 16;
        const float badd = bias[col];
        const int row0 = rowbase + mi * 16;
        const int batch = row0 >> 11, nr = row0 & 2047;
        bf16x4 o;
#pragma unroll
        for (int j = 0; j < 4; ++j) o[j] = (bf16_t)(acc[mi][ni][j] + badd);
        *(bf16x4*)(C + (long)batch * (2048 * 1024) + (long)col * 2048 + nr) = o;
      }
  }
}

// ---------------------------------------------------------------------------
extern "C" void kernel_launch(void* const* d_in, const int* in_sizes, int n_in,
                              void* d_out, int out_size, void* d_ws, size_t ws_size,
                              hipStream_t stream) {
  const int b = 4, n = 2048, d = 1024;
  const long nd  = (long)n * d;
  const long bn  = (long)b * n;
  const long bnd = bn * d;
  const long ddl = (long)d * d;
  const long nn  = (long)n * n;

  const float* q  = (const float*)d_in[0];
  const float* k  = (const float*)d_in[1];
  const float* v  = (const float*)d_in[2];
  const float* Wq = (const float*)d_in[3];
  const float* bq = (const float*)d_in[4];
  const float* Wk = (const float*)d_in[5];
  const float* bk = (const float*)d_in[6];
  const float* Wv = (const float*)d_in[7];
  const float* bv = (const float*)d_in[8];
  const float* Wo = (const float*)d_in[9];
  const float* bo = (const float*)d_in[10];

  bf16_t* ws  = (bf16_t*)d_ws;
  bf16_t* WqB = ws;
  bf16_t* WkB = WqB + ddl;
  bf16_t* WvB = WkB + ddl;
  bf16_t* WoB = WvB + ddl;
  bf16_t* qpB = WoB + ddl;
  bf16_t* kpB = qpB + bnd;
  bf16_t* vpT = kpB + bnd;       // per-batch [d][n] (written by V-proj epilogue)
  bf16_t* S   = vpT + bnd;
  bf16_t* yT  = S + (long)b * nn;
  const size_t need = (size_t)(4 * ddl + 4 * bnd + (long)b * nn) * 2;
  if (ws_size < need) return;

  dim3 blk(256);

  // fp32 -> bf16 converts: weights only
  CvtArgs ca;
  ca.src[0] = Wq; ca.dst[0] = WqB; ca.n4[0] = ddl / 4;
  ca.src[1] = Wk; ca.dst[1] = WkB; ca.n4[1] = ddl / 4;
  ca.src[2] = Wv; ca.dst[2] = WvB; ca.n4[2] = ddl / 4;
  ca.src[3] = Wo; ca.dst[3] = WoB; ca.n4[3] = ddl / 4;
  cvt_all<<<dim3(256, 4), blk, 0, stream>>>(ca);

  // fused QKV projections from fp32 inputs: grid (8, 64, 3) = 1536 blocks
  QkvArgsF qa;
  qa.A[0] = q; qa.W[0] = WqB; qa.bias[0] = bq; qa.C[0] = qpB;
  qa.A[1] = k; qa.W[1] = WkB; qa.bias[1] = bk; qa.C[1] = kpB;
  qa.A[2] = v; qa.W[2] = WvB; qa.bias[2] = bv; qa.C[2] = vpT;
  gemm_qkv_f32a<<<dim3(d / 128, bn / 128, 3), blk, 0, stream>>>(qa, d, d);

  // scores: S[z] = qp[z] x kp[z]^T * (1/32), 8-phase, causal tile-skip
  G8Args sa = {};
  sa.A[0] = qpB; sa.W[0] = kpB; sa.C[0] = S;
  sa.sA = nd; sa.sB = nd; sa.sC = nn;
  gemm8<1><<<dim3(n / 256, n / 256, b), dim3(512), 0, stream>>>(sa);

  // causal softmax in place (bounded to the straddle tile)
  softmax_causal<<<dim3(n, b), blk, 0, stream>>>(S, n, nn);

  // yT[z] = vpT[z] x P[z]^T   (K bounded per N-tile by causality)
  gemm_bt<true, false, true><<<dim3(n / 128, d / 128, b), blk, 0, stream>>>(
      vpT, S, nullptr, yT, n, n, 1.f, nd, nn, nd, 2);

  // out = y2 x Wo^T + bo ; y2 flat == yT flat, fp32 out
  gemm_bt<false, true, false><<<dim3(d / 128, bn / 128, 1), blk, 0, stream>>>(
      yT, WoB, bo, (float*)d_out, d, d, 1.f, 0, 0, 0, 4);
}